// Round 11
// baseline (321.110 us; speedup 1.0000x reference)
//
#include <hip/hip_runtime.h>
#include <math.h>

// Problem dims (fixed by setup_inputs)
#define DD    512
#define CNUM  64
#define SHOTS 16
#define NSUP  1024
#define QNQ   2048
#define REGP  0.1f
#define XKS   4      // xmu split-K parts

typedef __attribute__((ext_vector_type(8))) short short8;   // 8 bf16 = 4 VGPRs
typedef __attribute__((ext_vector_type(4))) float f32x4;

// bf16 round-to-nearest-even, raw bits (no header API dependence)
__device__ __forceinline__ unsigned short f2bf(float f) {
  unsigned int u = __float_as_uint(f);
  unsigned int r = (u + 0x7fffu + ((u >> 16) & 1u)) >> 16;
  return (unsigned short)r;
}
__device__ __forceinline__ float bf2f(unsigned short h) {
  return __uint_as_float((unsigned int)h << 16);
}

// ---------------- workspace layout (in floats) ----------------
static constexpr size_t OFF_L     = 0;                       // 512*512
static constexpr size_t OFF_W     = OFF_L     + 512*512;     // 512*512
static constexpr size_t OFF_MU    = OFF_W     + 512*512;     // 64*512
static constexpr size_t OFF_Y     = OFF_MU    + 64*512;      // 3136*512
static constexpr size_t OFF_Z     = OFF_Y     + 3136*512;    // 3136
static constexpr size_t OFF_WM    = OFF_Z     + 3136;        // 512
static constexpr size_t OFF_U     = OFF_WM    + 512;         // 512
static constexpr size_t OFF_CONST = OFF_U     + 512;         // 16
static constexpr size_t OFF_IDX   = OFF_CONST + 16;          // 1024 ints
static constexpr size_t OFF_RMAP  = OFF_IDX   + 1024;        // 1088 ints
static constexpr size_t OFF_ZG    = OFF_RMAP  + 1088;        // 1088
static constexpr size_t OFF_VMU   = OFF_ZG    + 1088;        // 1088
static constexpr size_t OFF_MUBMU = OFF_VMU   + 1088;        // 64
static constexpr size_t OFF_MUN   = OFF_MUBMU + 64;          // 64
static constexpr size_t OFF_MINV  = OFF_MUN   + 64;          // 64*289
static constexpr size_t OFF_BIAS  = OFF_MINV  + 64*289;      // 64
static constexpr size_t OFF_QB    = OFF_BIAS  + 64;          // 2048
static constexpr size_t OFF_QNRM  = OFF_QB    + 2048;        // 2048
static constexpr size_t OFF_XMU   = OFF_QNRM  + 2048;        // XKS*2048*64
static constexpr size_t OFF_RG    = OFF_XMU   + (size_t)XKS*2048*64; // 1088*2048
static constexpr size_t OFF_RG2   = OFF_RG    + 1088*2048;   // 1088*2048
static constexpr size_t OFF_P     = OFF_RG2   + 1088*2048;   // 3136*1024 bf16 (1.6M floats)

// consts: 0 kap, 1 scale, 2 common, 3 coef, 4 bias0, 5 jlast,
// 6 cmu_m, 7 cmu_x, 8 D*log(scale), 9 Jinv_last, 10 c_sm, 11 logdetB

// ============ F1: L/W init + consts + classidx + mu/mun + diag-inv ============
// All block ranges are self-sufficient (no cross-block deps within the launch).
__global__ __launch_bounds__(256) void f_init(const float* tdiag, const float* tlow,
    const float* kappa, const float* nu, const int* labels, const float* Xs,
    const float* m, float* L, float* W, float* cst, int* idx, int* rowmap,
    float* mu, float* mun) {
  __shared__ float sh[2 * 64 * 68];   // 34.8 KB union
  __shared__ int sidx[SHOTS];
  int b = blockIdx.x, tid = threadIdx.x;
  if (b < 1024) {
    int t = b * 256 + tid;
    int i = t >> 9, j = t & 511;
    L[t] = (i == j) ? fabsf(tdiag[i]) : (i > j ? tlow[t] : 0.0f);
    if ((i >> 6) < (j >> 6)) W[t] = 0.0f;   // only strict-upper 64-blocks need zeros
  } else if (b == 1024) {
    if (tid == 0) {
      float kap = fabsf(kappa[0]) + 1e-6f;
      float nu_ = fmaxf(nu[0], (float)(DD - 1) + 1e-6f);
      float common = nu_ + (float)SHOTS + 1.0f - (float)DD;
      float scale = (kap + SHOTS + 1.0f) / ((nu_ + SHOTS - DD + 1.0f) * (kap + SHOTS));
      cst[0] = kap;
      cst[1] = scale;
      cst[2] = common;
      cst[3] = 0.5f * (common + DD);
      cst[4] = lgammaf(0.5f * (common + DD)) - lgammaf(0.5f * common)
               - 0.5f * (float)DD * logf(common);
      cst[5] = -(kap + SHOTS);
      cst[6] = kap / (kap + SHOTS);
      cst[7] = 1.0f / (kap + SHOTS);
      cst[8] = (float)DD * logf(scale);
      cst[9] = -1.0f / (kap + SHOTS);
    }
  } else if (b < 1089) {
    // classidx + rowmap (global)
    int c = b - 1025;
    if (tid < 64) {
      int lane = tid, cnt = 0;
      for (int i0 = 0; i0 < NSUP; i0 += 64) {
        int lab = labels[i0 + lane];
        unsigned long long mm = __ballot(lab == c);
        if (lab == c) {
          int pos = cnt + __popcll(mm & ((1ull << lane) - 1ull));
          if (pos < SHOTS) idx[c * SHOTS + pos] = i0 + lane;
        }
        cnt += __popcll(mm);
      }
    }
    __syncthreads();
    if (tid < 17)
      rowmap[c * 17 + tid] = (tid < SHOTS) ? (QNQ + idx[c * SHOTS + tid])
                                           : (QNQ + NSUP + c);
  } else if (b < 1153) {
    // mu/mun with locally re-derived idx + kappa coefficients
    int c = b - 1089;
    if (tid < 64) {
      int lane = tid, cnt = 0;
      for (int i0 = 0; i0 < NSUP; i0 += 64) {
        int lab = labels[i0 + lane];
        unsigned long long mm = __ballot(lab == c);
        if (lab == c) {
          int pos = cnt + __popcll(mm & ((1ull << lane) - 1ull));
          if (pos < SHOTS) sidx[pos] = i0 + lane;
        }
        cnt += __popcll(mm);
      }
    }
    __syncthreads();
    float kap = fabsf(kappa[0]) + 1e-6f;
    float cm = kap / (kap + SHOTS), cx = 1.0f / (kap + SHOTS);
    float* red = sh;
    float acc = 0.0f;
    for (int d = tid; d < DD; d += 256) {
      float s = 0.0f;
      for (int sh_ = 0; sh_ < SHOTS; sh_++)
        s += Xs[(size_t)sidx[sh_] * DD + d];
      float v = cm * m[d] + cx * s;
      mu[(size_t)c * DD + d] = v;
      acc += v * v;
    }
    red[tid] = acc;
    __syncthreads();
    for (int off = 128; off > 0; off >>= 1) {
      if (tid < off) red[tid] += red[tid + off];
      __syncthreads();
    }
    if (tid == 0) mun[c] = red[0];
  } else {
    // diag 64x64 inverse, L-tile built directly from tdiag/tlow
    int jb = b - 1153;
    float* Ld = sh;             // [64][68]
    float* Wd = sh + 64 * 68;   // [64][68]
    for (int t = tid; t < 4096; t += 256) {
      int r = t >> 6, c = t & 63;
      int gr = jb * 64 + r;
      float v = (r == c) ? fabsf(tdiag[gr])
              : (r > c ? tlow[(size_t)gr * DD + jb * 64 + c] : 0.0f);
      Ld[r * 68 + c] = v;
    }
    __syncthreads();
    if (tid < 64) {
      // thread t owns column t of the inverse
      for (int i = 0; i < 64; i++) {
        float w = (i == tid) ? 1.0f : 0.0f;
        for (int k = 0; k < i; k++) w -= Ld[i * 68 + k] * Wd[k * 68 + tid];
        Wd[i * 68 + tid] = w / Ld[i * 68 + i];
      }
    }
    __syncthreads();
    float* Wblk = W + (size_t)(jb * 64) * DD + jb * 64;
    for (int t = tid; t < 4096; t += 256)
      Wblk[(size_t)(t >> 6) * DD + (t & 63)] = Wd[(t >> 6) * 68 + (t & 63)];
  }
}

// 64x64 NN GEMM tile on caller LDS (stride 68): Cd = sgn * A[:,k0:k1] * B[k0:k1,:]
__device__ __forceinline__ void nn64_sh(float* As, float* Bs,
    const float* __restrict__ A, int lda, const float* __restrict__ B, int ldb,
    float* __restrict__ Cd, int ldc, int k0, int k1, float sgn) {
  int tid = threadIdx.x, tr = tid >> 4, tc = tid & 15;
  float acc[4][4] = {};
  for (int kc = k0; kc < k1; kc += 64) {
    #pragma unroll
    for (int p = 0; p < 4; p++) {
      int f4 = tid + 256 * p;
      int row = f4 >> 4, c4 = f4 & 15;
      *(float4*)&As[row * 68 + c4 * 4] = *(const float4*)(A + (size_t)row * lda + kc + c4 * 4);
      *(float4*)&Bs[row * 68 + c4 * 4] = *(const float4*)(B + (size_t)(kc + row) * ldb + c4 * 4);
    }
    __syncthreads();
    #pragma unroll
    for (int kk = 0; kk < 64; kk++) {
      float a[4];
      #pragma unroll
      for (int x = 0; x < 4; x++) a[x] = As[(tr * 4 + x) * 68 + kk];
      float4 bv = *(const float4*)&Bs[kk * 68 + tc * 4];
      float bb[4] = {bv.x, bv.y, bv.z, bv.w};
      #pragma unroll
      for (int x = 0; x < 4; x++)
        #pragma unroll
        for (int y = 0; y < 4; y++) acc[x][y] += a[x] * bb[y];
    }
    __syncthreads();
  }
  #pragma unroll
  for (int x = 0; x < 4; x++) {
    float4 v = make_float4(sgn * acc[x][0], sgn * acc[x][1],
                           sgn * acc[x][2], sgn * acc[x][3]);
    *(float4*)(Cd + (size_t)(tr * 4 + x) * ldc + tc * 4) = v;
  }
}

#define GBK 16
// ============ triT level 128 fused with xmu partials ============
__global__ __launch_bounds__(256) void k_triT128_xmu(const float* __restrict__ L,
    const float* __restrict__ W, float* __restrict__ T,
    const float* __restrict__ Xq, const float* __restrict__ Mu,
    float* __restrict__ xmup) {
  __shared__ float sh[2 * 64 * 68];
  int b = blockIdx.x, tid = threadIdx.x;
  if (b < 4) {              // triT, s=128: h=64, tiles=1
    int g = b, base = g * 128;
    const float* A = L + (size_t)(base + 64) * DD + base;
    const float* B = W + (size_t)base * DD + base;
    float* Cd = T + (size_t)g * 64 * 64;
    nn64_sh(sh, sh + 64 * 68, A, DD, B, DD, Cd, 64, 0, 64, 1.0f);
  } else {                  // xmu partials: 32 q-rows, split-K=4
    float* As = sh;               // stride 36, 16 rows
    float* Bs = sh + 16 * 36;     // stride 68, 16 rows
    int xb = b - 4;
    int bm = (xb & 63) * 32, kq = xb >> 6;
    int tr = tid >> 4, tc = tid & 15;
    float acc[2][4] = {};
    int k0s = kq * (DD / XKS), k0e = k0s + DD / XKS;
    for (int k0 = k0s; k0 < k0e; k0 += GBK) {
      if (tid < 128) {
        int row = tid >> 2, k4 = tid & 3;
        float4 v = *(const float4*)(Xq + (size_t)(bm + row) * DD + k0 + k4 * 4);
        As[(k4 * 4 + 0) * 36 + row] = v.x; As[(k4 * 4 + 1) * 36 + row] = v.y;
        As[(k4 * 4 + 2) * 36 + row] = v.z; As[(k4 * 4 + 3) * 36 + row] = v.w;
      }
      {
        int row = tid >> 2, k4 = tid & 3;
        float4 v = *(const float4*)(Mu + (size_t)row * DD + k0 + k4 * 4);
        Bs[(k4 * 4 + 0) * 68 + row] = v.x; Bs[(k4 * 4 + 1) * 68 + row] = v.y;
        Bs[(k4 * 4 + 2) * 68 + row] = v.z; Bs[(k4 * 4 + 3) * 68 + row] = v.w;
      }
      __syncthreads();
      #pragma unroll
      for (int kk = 0; kk < GBK; kk++) {
        float a[2] = {As[kk * 36 + tr * 2], As[kk * 36 + tr * 2 + 1]};
        float4 b0 = *(const float4*)&Bs[kk * 68 + tc * 4];
        float bb[4] = {b0.x, b0.y, b0.z, b0.w};
        #pragma unroll
        for (int x = 0; x < 2; x++)
          #pragma unroll
          for (int y = 0; y < 4; y++) acc[x][y] += a[x] * bb[y];
      }
      __syncthreads();
    }
    #pragma unroll
    for (int x = 0; x < 2; x++) {
      int q = bm + tr * 2 + x;
      float4 v = make_float4(acc[x][0], acc[x][1], acc[x][2], acc[x][3]);
      *(float4*)(xmup + ((size_t)kq * QNQ + q) * CNUM + tc * 4) = v;
    }
  }
}

// generic trinv doubling levels
__global__ __launch_bounds__(256) void k_triT(const float* __restrict__ L,
                                              const float* __restrict__ W,
                                              float* __restrict__ T, int s) {
  __shared__ float sh[2 * 64 * 68];
  int h = s >> 1, tiles = h >> 6, per = tiles * tiles;
  int g = blockIdx.x / per, rem = blockIdx.x % per;
  int ti = rem / tiles, tj = rem % tiles;
  int base = g * s;
  const float* A = L + (size_t)(base + h + ti * 64) * DD + base;
  const float* B = W + (size_t)base * DD + base + tj * 64;
  float* Cd = T + (size_t)g * h * h + (size_t)(ti * 64) * h + tj * 64;
  nn64_sh(sh, sh + 64 * 68, A, DD, B, DD, Cd, h, tj * 64, h, 1.0f);
}

__global__ __launch_bounds__(256) void k_triX(float* __restrict__ W,
                                              const float* __restrict__ T, int s) {
  __shared__ float sh[2 * 64 * 68];
  int h = s >> 1, tiles = h >> 6, per = tiles * tiles;
  int g = blockIdx.x / per, rem = blockIdx.x % per;
  int ti = rem / tiles, tj = rem % tiles;
  int base = g * s;
  const float* A = W + (size_t)(base + h + ti * 64) * DD + base + h;
  const float* B = T + (size_t)g * h * h + tj * 64;
  float* Cd = W + (size_t)(base + h + ti * 64) * DD + base + tj * 64;
  nn64_sh(sh, sh + 64 * 68, A, DD, B, h, Cd, DD, 0, (ti + 1) * 64, -1.0f);
}

// ============ F3: Y-GEMM (64x64, tri-skip) + wm; epilogue also writes P=[Yh|Yl] bf16 ============
__global__ __launch_bounds__(256) void f_y_wm(const float* __restrict__ Xq,
    const float* __restrict__ Xs, const float* __restrict__ Mu,
    const float* __restrict__ W, const float* __restrict__ m,
    float* __restrict__ Y, unsigned short* __restrict__ Pm,
    float* __restrict__ wm) {
  __shared__ float As[GBK][68];
  __shared__ float Bs[GBK][68];
  int b = blockIdx.x, tid = threadIdx.x;
  if (b < 392) {            // Y = [Xq; Xs; mu] @ W^T; 49 m-tiles x 8 n-tiles
    int mt = b >> 3, nt = b & 7;
    int bm = mt * 64, bn = nt * 64;
    const float* A; int aOff;
    if (bm < QNQ)             { A = Xq; aOff = bm; }
    else if (bm < QNQ + NSUP) { A = Xs; aOff = bm - QNQ; }
    else                      { A = Mu; aOff = bm - QNQ - NSUP; }
    int tr = tid >> 4, tc = tid & 15;
    float acc[4][4] = {};
    int kend = bn + 64;     // W lower-triangular
    for (int k0 = 0; k0 < kend; k0 += GBK) {
      int row = tid >> 2, k4 = tid & 3;
      float4 v = *(const float4*)(A + (size_t)(aOff + row) * DD + k0 + k4 * 4);
      As[k4 * 4 + 0][row] = v.x; As[k4 * 4 + 1][row] = v.y;
      As[k4 * 4 + 2][row] = v.z; As[k4 * 4 + 3][row] = v.w;
      float4 w = *(const float4*)(W + (size_t)(bn + row) * DD + k0 + k4 * 4);
      Bs[k4 * 4 + 0][row] = w.x; Bs[k4 * 4 + 1][row] = w.y;
      Bs[k4 * 4 + 2][row] = w.z; Bs[k4 * 4 + 3][row] = w.w;
      __syncthreads();
      #pragma unroll
      for (int kk = 0; kk < GBK; kk++) {
        float4 a0 = *(const float4*)&As[kk][tr * 4];
        float4 b0 = *(const float4*)&Bs[kk][tc * 4];
        float a[4] = {a0.x, a0.y, a0.z, a0.w};
        float bb[4] = {b0.x, b0.y, b0.z, b0.w};
        #pragma unroll
        for (int x = 0; x < 4; x++)
          #pragma unroll
          for (int y = 0; y < 4; y++) acc[x][y] += a[x] * bb[y];
      }
      __syncthreads();
    }
    #pragma unroll
    for (int x = 0; x < 4; x++) {
      int row = bm + tr * 4 + x;
      float4 v = make_float4(acc[x][0], acc[x][1], acc[x][2], acc[x][3]);
      *(float4*)(Y + (size_t)row * DD + bn + tc * 4) = v;
      // bf16 hi/lo split for the MFMA Rg path
      ushort4 hi, lo;
      hi.x = f2bf(v.x); lo.x = f2bf(v.x - bf2f(hi.x));
      hi.y = f2bf(v.y); lo.y = f2bf(v.y - bf2f(hi.y));
      hi.z = f2bf(v.z); lo.z = f2bf(v.z - bf2f(hi.z));
      hi.w = f2bf(v.w); lo.w = f2bf(v.w - bf2f(hi.w));
      *(ushort4*)(Pm + (size_t)row * 1024 + bn + tc * 4) = hi;
      *(ushort4*)(Pm + (size_t)row * 1024 + 512 + bn + tc * 4) = lo;
    }
  } else {                  // wm[row] = W[row,:] . m  (4 rows/block)
    int wave = tid >> 6, lane = tid & 63;
    int row = (b - 392) * 4 + wave;
    float s = 0.0f;
    for (int j = lane; j < DD; j += 64) s += W[(size_t)row * DD + j] * m[j];
    for (int off = 32; off > 0; off >>= 1) s += __shfl_down(s, off);
    if (lane == 0) wm[row] = s;
  }
}

// fused: blocks 0..511 compute u[j]; block 512 computes SM consts
__global__ __launch_bounds__(256) void k_uB(const float* W, const float* L,
                                            const float* wm, float* u, float* cst) {
  __shared__ float red[256];
  __shared__ float red2[256];
  int b = blockIdx.x, tid = threadIdx.x;
  if (b < DD) {
    float s = 0.0f;
    for (int i = tid; i < DD; i += 256) s += W[(size_t)i * DD + b] * wm[i];
    red[tid] = s;
    __syncthreads();
    for (int off = 128; off > 0; off >>= 1) {
      if (tid < off) red[tid] += red[tid + off];
      __syncthreads();
    }
    if (tid == 0) u[b] = red[0];
  } else {
    float a = 0.0f, l = 0.0f;
    for (int t = tid; t < DD; t += 256) {
      float w = wm[t]; a += w * w;
      l += logf(fabsf(L[(size_t)t * DD + t]));
    }
    red[tid] = a; red2[tid] = l;
    __syncthreads();
    for (int off = 128; off > 0; off >>= 1) {
      if (tid < off) { red[tid] += red[tid + off]; red2[tid] += red2[tid + off]; }
      __syncthreads();
    }
    if (tid == 0) {
      float kap = cst[0], ss = red[0];
      cst[10] = kap / (1.0f + kap * ss);
      cst[11] = 2.0f * red2[0] + logf(1.0f + kap * ss);
    }
  }
}

// ============ F5: Rg via bf16-split MFMA (exact product over 2 passes) + query z ============
// Pass h=0: Rg  = P . P^T          (= ah*bh + al*bl)
// Pass h=1: Rg2 = P . P(k^512)^T   (= ah*bl + al*bh)
// Sum (done in k_logits) = exact (ah+al)(bh+bl) — representation error ~2^-17/elt.
__global__ __launch_bounds__(256) void f_z_rg(const unsigned short* __restrict__ Pm,
    const float* __restrict__ Y, const int* __restrict__ rowmap,
    const float* __restrict__ Xq, const float* __restrict__ u,
    const float* __restrict__ cst,
    float* __restrict__ Rg, float* __restrict__ Rg2,
    float* __restrict__ z, float* __restrict__ qn, float* __restrict__ qB) {
  int b = blockIdx.x, tid = threadIdx.x;
  if (b < 1088) {           // 17 m-tiles x 32 n-tiles x 2 passes, 64x64 out
    int half = b / 544, rem = b % 544;
    int bm = (rem >> 5) * 64, bn = (rem & 31) * 64;
    float* out = half ? Rg2 : Rg;
    int kxor = half ? 512 : 0;
    int lane = tid & 63, wave = tid >> 6;
    int wr = wave >> 1, wc = wave & 1;    // 2x2 waves -> 32x32 each
    int mrow = lane & 15, q = lane >> 4;  // A/B operand: row/col = lane&15, kgroup = lane>>4
    int ar0 = rowmap[bm + wr * 32 + mrow];
    int ar1 = rowmap[bm + wr * 32 + 16 + mrow];
    int br0 = bn + wc * 32 + mrow;
    int br1 = bn + wc * 32 + 16 + mrow;
    const short8* pa0 = (const short8*)(Pm + (size_t)ar0 * 1024 + q * 8);
    const short8* pa1 = (const short8*)(Pm + (size_t)ar1 * 1024 + q * 8);
    f32x4 acc00 = {}, acc01 = {}, acc10 = {}, acc11 = {};
    #pragma unroll 4
    for (int ks = 0; ks < 32; ks++) {
      int kA = ks * 32;
      int kB = (kA + q * 8) ^ kxor;
      short8 a0 = pa0[kA >> 3];
      short8 a1 = pa1[kA >> 3];
      short8 b0 = *(const short8*)(Pm + (size_t)br0 * 1024 + kB);
      short8 b1 = *(const short8*)(Pm + (size_t)br1 * 1024 + kB);
      acc00 = __builtin_amdgcn_mfma_f32_16x16x32_bf16(a0, b0, acc00, 0, 0, 0);
      acc01 = __builtin_amdgcn_mfma_f32_16x16x32_bf16(a0, b1, acc01, 0, 0, 0);
      acc10 = __builtin_amdgcn_mfma_f32_16x16x32_bf16(a1, b0, acc10, 0, 0, 0);
      acc11 = __builtin_amdgcn_mfma_f32_16x16x32_bf16(a1, b1, acc11, 0, 0, 0);
    }
    // C/D layout: row = (lane>>4)*4 + r, col = lane&15
    #pragma unroll
    for (int r = 0; r < 4; r++) {
      int row0 = bm + wr * 32 + q * 4 + r;
      int row1 = row0 + 16;
      int col0 = bn + wc * 32 + mrow;
      out[(size_t)row0 * QNQ + col0]      = acc00[r];
      out[(size_t)row0 * QNQ + col0 + 16] = acc01[r];
      out[(size_t)row1 * QNQ + col0]      = acc10[r];
      out[(size_t)row1 * QNQ + col0 + 16] = acc11[r];
    }
  } else {                  // query rows: z, qn, qB (4 rows/block)
    int wave = tid >> 6, lane = tid & 63;
    int row = (b - 1088) * 4 + wave;
    const float* src = Xq + (size_t)row * DD;
    const float* yr = Y + (size_t)row * DD;
    float s = 0.0f, s1 = 0.0f, s2 = 0.0f;
    for (int j4 = lane; j4 < 128; j4 += 64) {
      float4 v = *(const float4*)(src + j4 * 4);
      float4 uu = *(const float4*)(u + j4 * 4);
      s += v.x * uu.x + v.y * uu.y + v.z * uu.z + v.w * uu.w;
      s1 += v.x * v.x + v.y * v.y + v.z * v.z + v.w * v.w;
      float4 yv = *(const float4*)(yr + j4 * 4);
      s2 += yv.x * yv.x + yv.y * yv.y + yv.z * yv.z + yv.w * yv.w;
    }
    for (int off = 32; off > 0; off >>= 1) {
      s += __shfl_down(s, off);
      s1 += __shfl_down(s1, off);
      s2 += __shfl_down(s2, off);
    }
    if (lane == 0) {
      z[row] = s;
      qn[row] = s1;
      qB[row] = s2 - cst[10] * s * s;
    }
  }
}

// ============ F6: per-class Gram (zs = Y.wm in-kernel) + GJ inverse + bias ============
#define YSTRIDE 516
__global__ __launch_bounds__(256) void k_gramminv(const float* Y, const float* wm,
    const int* rowmap, const float* cst, float* zg, float* Vmu, float* muBmu,
    float* Minv, float* bias) {
  __shared__ float Ys[17 * YSTRIDE];
  __shared__ float zs[17];
  __shared__ float aug[17][35];
  __shared__ float colk[17];
  __shared__ int pivrow;
  __shared__ float detacc;
  int c = blockIdx.x, tid = threadIdx.x;
  for (int t = tid; t < 17 * 128; t += 256) {
    int r = t >> 7, col = t & 127;
    *(float4*)&Ys[r * YSTRIDE + col * 4] =
        *(const float4*)(Y + (size_t)rowmap[c * 17 + r] * DD + col * 4);
  }
  __syncthreads();
  // zs[a] = Y_row(a) . wm   (wave w owns rows w, w+4, ...)
  {
    int wave = tid >> 6, lane = tid & 63;
    for (int a = wave; a < 17; a += 4) {
      float s = 0.0f;
      for (int j = lane; j < DD; j += 64) s += Ys[a * YSTRIDE + j] * wm[j];
      for (int off = 32; off > 0; off >>= 1) s += __shfl_down(s, off);
      if (lane == 0) zs[a] = s;
    }
  }
  __syncthreads();
  float csm = cst[10];
  for (int e = tid; e < 289; e += 256) {
    int a = e / 17, bb = e % 17;
    const float* ra = &Ys[a * YSTRIDE];
    const float* rb = &Ys[bb * YSTRIDE];
    float s = 0.0f;
    for (int k = 0; k < 128; k++) {
      float4 va = *(const float4*)&ra[k * 4];
      float4 vb = *(const float4*)&rb[k * 4];
      s += va.x * vb.x + va.y * vb.y + va.z * vb.z + va.w * vb.w;
    }
    float g = s - csm * zs[a] * zs[bb];
    if (a == bb) g += (a < 16) ? 1.0f : cst[9];
    aug[a][bb] = g;
    aug[a][17 + bb] = (a == bb) ? 1.0f : 0.0f;
  }
  __syncthreads();
  if (tid < 17) {
    float gv = aug[tid][16];
    if (tid == 16) gv -= cst[9];
    Vmu[c * 17 + tid] = gv;
    if (tid == 16) muBmu[c] = gv;
    zg[c * 17 + tid] = zs[tid];
  }
  if (tid == 0) detacc = 0.0f;
  __syncthreads();
  for (int k = 0; k < 17; k++) {
    if (tid == 0) {
      int p = k; float best = fabsf(aug[k][k]);
      for (int r = k + 1; r < 17; r++) {
        float v = fabsf(aug[r][k]);
        if (v > best) { best = v; p = r; }
      }
      pivrow = p;
    }
    __syncthreads();
    int p = pivrow;
    if (p != k) {
      for (int cc = tid; cc < 34; cc += 256) {
        float tmp = aug[k][cc]; aug[k][cc] = aug[p][cc]; aug[p][cc] = tmp;
      }
    }
    __syncthreads();
    if (tid == 0) detacc += logf(fabsf(aug[k][k]));
    if (tid < 17) colk[tid] = aug[tid][k];
    __syncthreads();
    float invp = 1.0f / aug[k][k];
    for (int cc = tid; cc < 34; cc += 256) aug[k][cc] *= invp;
    __syncthreads();
    for (int t = tid; t < 17 * 34; t += 256) {
      int r = t / 34, cc = t % 34;
      if (r != k) aug[r][cc] -= colk[r] * aug[k][cc];
    }
    __syncthreads();
  }
  for (int t = tid; t < 289; t += 256) Minv[(size_t)c * 289 + t] = aug[t / 17][17 + t % 17];
  if (tid == 0) {
    float slog = logf(fabsf(cst[5])) + detacc;
    float logdetSigma = cst[8] + cst[11] + slog;
    bias[c] = cst[4] - 0.5f * logdetSigma;
  }
}

// final epilogue: Woodbury-corrected Mahalanobis -> logits[q,c]
__global__ __launch_bounds__(256) void k_logits(const float* __restrict__ Rg,
    const float* __restrict__ Rg2, const float* z, const float* zg,
    const float* Vmu, const float* muBmu, const float* mun, const float* qB,
    const float* qn, const float* xmup, const float* Minv, const float* bias,
    const float* cst, float* out) {
  __shared__ float Ms[289], Vs[17], Zs[17];
  int c = blockIdx.y;
  int q = blockIdx.x * 256 + threadIdx.x;
  for (int t = threadIdx.x; t < 289; t += 256) Ms[t] = Minv[(size_t)c * 289 + t];
  if (threadIdx.x < 17) {
    Vs[threadIdx.x] = Vmu[c * 17 + threadIdx.x];
    Zs[threadIdx.x] = zg[c * 17 + threadIdx.x];
  }
  __syncthreads();
  float csm = cst[10], scale = cst[1], common = cst[2], coef = cst[3];
  float zq = z[q];
  float r[17];
  float xBmu = 0.0f;
  for (int a = 0; a < 17; a++) {
    size_t off = (size_t)(c * 17 + a) * QNQ + q;
    float raw = Rg[off] + Rg2[off] - csm * Zs[a] * zq;
    if (a == 16) xBmu = raw;
    r[a] = raw - Vs[a];
  }
  float quadB = qB[q] - 2.0f * xBmu + muBmu[c];
  float corr = 0.0f;
  for (int a = 0; a < 17; a++) {
    float e = 0.0f;
    for (int bb = 0; bb < 17; bb++) e += Ms[a * 17 + bb] * r[bb];
    corr += r[a] * e;
  }
  float distB = (quadB - corr) / scale;
  float xm = 0.0f;
  #pragma unroll
  for (int p = 0; p < XKS; p++)
    xm += xmup[((size_t)p * QNQ + q) * CNUM + c];
  float dn = qn[q] - 2.0f * xm + mun[c];
  float dist = (1.0f - REGP) * distB + REGP * dn;
  out[(size_t)q * CNUM + c] = bias[c] - coef * log1pf(dist / common);
}

// ---------------- host ----------------
extern "C" void kernel_launch(void* const* d_in, const int* in_sizes, int n_in,
                              void* d_out, int out_size, void* d_ws, size_t ws_size,
                              hipStream_t stream) {
  const float* Xs    = (const float*)d_in[0];
  const int*   labels= (const int*)d_in[1];
  const float* Xq    = (const float*)d_in[2];
  const float* m     = (const float*)d_in[3];
  const float* kappa = (const float*)d_in[4];
  const float* nu    = (const float*)d_in[5];
  const float* tdiag = (const float*)d_in[6];
  const float* tlow  = (const float*)d_in[7];
  float* ws = (float*)d_ws;
  float* L    = ws + OFF_L;
  float* W    = ws + OFF_W;
  float* mu   = ws + OFF_MU;
  float* Y    = ws + OFF_Y;
  float* z    = ws + OFF_Z;
  float* wm   = ws + OFF_WM;
  float* u    = ws + OFF_U;
  float* cst  = ws + OFF_CONST;
  int*   idx  = (int*)(ws + OFF_IDX);
  int*   rmap = (int*)(ws + OFF_RMAP);
  float* zg   = ws + OFF_ZG;
  float* Vmu  = ws + OFF_VMU;
  float* muBmu= ws + OFF_MUBMU;
  float* mun  = ws + OFF_MUN;
  float* Minv = ws + OFF_MINV;
  float* bias = ws + OFF_BIAS;
  float* qB   = ws + OFF_QB;
  float* qn   = ws + OFF_QNRM;
  float* xmup = ws + OFF_XMU;
  float* Rg   = ws + OFF_RG;
  float* Rg2  = ws + OFF_RG2;
  unsigned short* P = (unsigned short*)(ws + OFF_P);
  float* Ttmp = ws + OFF_RG;       // trinv scratch, reused (Rg written later)
  float* out  = (float*)d_out;

  // F1: L/W init + consts + classidx + mu/mun + diag inverses (self-sufficient ranges)
  f_init<<<1161, 256, 0, stream>>>(tdiag, tlow, kappa, nu, labels, Xs, m,
                                   L, W, cst, idx, rmap, mu, mun);
  // trinv recursive doubling; level-128 T fused with xmu partials
  k_triT128_xmu<<<260, 256, 0, stream>>>(L, W, Ttmp, Xq, mu, xmup);
  k_triX<<<4, 256, 0, stream>>>(W, Ttmp, 128);
  k_triT<<<8, 256, 0, stream>>>(L, W, Ttmp, 256);
  k_triX<<<8, 256, 0, stream>>>(W, Ttmp, 256);
  k_triT<<<16, 256, 0, stream>>>(L, W, Ttmp, 512);
  k_triX<<<16, 256, 0, stream>>>(W, Ttmp, 512);
  // Y GEMM (64x64, tri-skip) + wm; also emits P = [Yh|Yl] bf16
  f_y_wm<<<520, 256, 0, stream>>>(Xq, Xs, mu, W, m, Y, P, wm);
  // u = W^T wm + SM consts
  k_uB<<<513, 256, 0, stream>>>(W, L, wm, u, cst);
  // Rg via 2-pass bf16-split MFMA + query z/qn/qB
  f_z_rg<<<1088 + 512, 256, 0, stream>>>(P, Y, rmap, Xq, u, cst, Rg, Rg2, z, qn, qB);
  // Gram (zs = Y.wm) + 17x17 inverse + bias
  k_gramminv<<<64, 256, 0, stream>>>(Y, wm, rmap, cst, zg, Vmu, muBmu, Minv, bias);
  k_logits<<<dim3(QNQ / 256, CNUM), 256, 0, stream>>>(Rg, Rg2, z, zg, Vmu, muBmu,
                                                      mun, qB, qn, xmup, Minv, bias,
                                                      cst, out);
  (void)in_sizes; (void)n_in; (void)out_size; (void)ws_size;
}

// Round 12
// 268.410 us; speedup vs baseline: 1.1963x; 1.1963x over previous
//
#include <hip/hip_runtime.h>
#include <math.h>

// Problem dims (fixed by setup_inputs)
#define DD    512
#define CNUM  64
#define SHOTS 16
#define NSUP  1024
#define QNQ   2048
#define REGP  0.1f
#define XKS   4      // xmu split-K parts

typedef __attribute__((ext_vector_type(8))) short short8;   // 8 bf16 = 4 VGPRs
typedef __attribute__((ext_vector_type(4))) float f32x4;

// bf16 round-to-nearest-even, raw bits
__device__ __forceinline__ unsigned short f2bf(float f) {
  unsigned int u = __float_as_uint(f);
  unsigned int r = (u + 0x7fffu + ((u >> 16) & 1u)) >> 16;
  return (unsigned short)r;
}
__device__ __forceinline__ float bf2f(unsigned short h) {
  return __uint_as_float((unsigned int)h << 16);
}

// ---------------- workspace layout (in floats) ----------------
static constexpr size_t OFF_L     = 0;                       // 512*512
static constexpr size_t OFF_W     = OFF_L     + 512*512;     // 512*512
static constexpr size_t OFF_MU    = OFF_W     + 512*512;     // 64*512
static constexpr size_t OFF_Y     = OFF_MU    + 64*512;      // 3136*512
static constexpr size_t OFF_Z     = OFF_Y     + 3136*512;    // 3136
static constexpr size_t OFF_WM    = OFF_Z     + 3136;        // 512
static constexpr size_t OFF_U     = OFF_WM    + 512;         // 512
static constexpr size_t OFF_CONST = OFF_U     + 512;         // 16
static constexpr size_t OFF_IDX   = OFF_CONST + 16;          // 1024 ints
static constexpr size_t OFF_RMAP  = OFF_IDX   + 1024;        // 1088 ints
static constexpr size_t OFF_ZG    = OFF_RMAP  + 1088;        // 1088
static constexpr size_t OFF_VMU   = OFF_ZG    + 1088;        // 1088
static constexpr size_t OFF_MUBMU = OFF_VMU   + 1088;        // 64
static constexpr size_t OFF_MUN   = OFF_MUBMU + 64;          // 64
static constexpr size_t OFF_MINV  = OFF_MUN   + 64;          // 64*289
static constexpr size_t OFF_BIAS  = OFF_MINV  + 64*289;      // 64
static constexpr size_t OFF_QB    = OFF_BIAS  + 64;          // 2048
static constexpr size_t OFF_QNRM  = OFF_QB    + 2048;        // 2048
static constexpr size_t OFF_XMU   = OFF_QNRM  + 2048;        // XKS*2048*64
static constexpr size_t OFF_RG    = OFF_XMU   + (size_t)XKS*2048*64; // 1088*2048
static constexpr size_t OFF_RG2   = OFF_RG    + 1088*2048;   // 1088*2048
static constexpr size_t OFF_P     = OFF_RG2   + 1088*2048;   // 3136*1024 bf16

// consts: 0 kap, 1 scale, 2 common, 3 coef, 4 bias0, 5 jlast,
// 6 cmu_m, 7 cmu_x, 8 D*log(scale), 9 Jinv_last, 10 c_sm, 11 logdetB

// ============ F1: L/W init + consts + classidx + mu/mun + diag-inv ============
__global__ __launch_bounds__(256) void f_init(const float* tdiag, const float* tlow,
    const float* kappa, const float* nu, const int* labels, const float* Xs,
    const float* m, float* L, float* W, float* cst, int* idx, int* rowmap,
    float* mu, float* mun) {
  __shared__ float sh[2 * 64 * 68];   // 34.8 KB union
  __shared__ int sidx[SHOTS];
  int b = blockIdx.x, tid = threadIdx.x;
  if (b < 1024) {
    int t = b * 256 + tid;
    int i = t >> 9, j = t & 511;
    L[t] = (i == j) ? fabsf(tdiag[i]) : (i > j ? tlow[t] : 0.0f);
    if ((i >> 6) < (j >> 6)) W[t] = 0.0f;   // only strict-upper 64-blocks need zeros
  } else if (b == 1024) {
    if (tid == 0) {
      float kap = fabsf(kappa[0]) + 1e-6f;
      float nu_ = fmaxf(nu[0], (float)(DD - 1) + 1e-6f);
      float common = nu_ + (float)SHOTS + 1.0f - (float)DD;
      float scale = (kap + SHOTS + 1.0f) / ((nu_ + SHOTS - DD + 1.0f) * (kap + SHOTS));
      cst[0] = kap;
      cst[1] = scale;
      cst[2] = common;
      cst[3] = 0.5f * (common + DD);
      cst[4] = lgammaf(0.5f * (common + DD)) - lgammaf(0.5f * common)
               - 0.5f * (float)DD * logf(common);
      cst[5] = -(kap + SHOTS);
      cst[6] = kap / (kap + SHOTS);
      cst[7] = 1.0f / (kap + SHOTS);
      cst[8] = (float)DD * logf(scale);
      cst[9] = -1.0f / (kap + SHOTS);
    }
  } else if (b < 1089) {
    int c = b - 1025;
    if (tid < 64) {
      int lane = tid, cnt = 0;
      for (int i0 = 0; i0 < NSUP; i0 += 64) {
        int lab = labels[i0 + lane];
        unsigned long long mm = __ballot(lab == c);
        if (lab == c) {
          int pos = cnt + __popcll(mm & ((1ull << lane) - 1ull));
          if (pos < SHOTS) idx[c * SHOTS + pos] = i0 + lane;
        }
        cnt += __popcll(mm);
      }
    }
    __syncthreads();
    if (tid < 17)
      rowmap[c * 17 + tid] = (tid < SHOTS) ? (QNQ + idx[c * SHOTS + tid])
                                           : (QNQ + NSUP + c);
  } else if (b < 1153) {
    int c = b - 1089;
    if (tid < 64) {
      int lane = tid, cnt = 0;
      for (int i0 = 0; i0 < NSUP; i0 += 64) {
        int lab = labels[i0 + lane];
        unsigned long long mm = __ballot(lab == c);
        if (lab == c) {
          int pos = cnt + __popcll(mm & ((1ull << lane) - 1ull));
          if (pos < SHOTS) sidx[pos] = i0 + lane;
        }
        cnt += __popcll(mm);
      }
    }
    __syncthreads();
    float kap = fabsf(kappa[0]) + 1e-6f;
    float cm = kap / (kap + SHOTS), cx = 1.0f / (kap + SHOTS);
    float* red = sh;
    float acc = 0.0f;
    for (int d = tid; d < DD; d += 256) {
      float s = 0.0f;
      for (int sh_ = 0; sh_ < SHOTS; sh_++)
        s += Xs[(size_t)sidx[sh_] * DD + d];
      float v = cm * m[d] + cx * s;
      mu[(size_t)c * DD + d] = v;
      acc += v * v;
    }
    red[tid] = acc;
    __syncthreads();
    for (int off = 128; off > 0; off >>= 1) {
      if (tid < off) red[tid] += red[tid + off];
      __syncthreads();
    }
    if (tid == 0) mun[c] = red[0];
  } else {
    int jb = b - 1153;
    float* Ld = sh;             // [64][68]
    float* Wd = sh + 64 * 68;   // [64][68]
    for (int t = tid; t < 4096; t += 256) {
      int r = t >> 6, c = t & 63;
      int gr = jb * 64 + r;
      float v = (r == c) ? fabsf(tdiag[gr])
              : (r > c ? tlow[(size_t)gr * DD + jb * 64 + c] : 0.0f);
      Ld[r * 68 + c] = v;
    }
    __syncthreads();
    if (tid < 64) {
      for (int i = 0; i < 64; i++) {
        float w = (i == tid) ? 1.0f : 0.0f;
        for (int k = 0; k < i; k++) w -= Ld[i * 68 + k] * Wd[k * 68 + tid];
        Wd[i * 68 + tid] = w / Ld[i * 68 + i];
      }
    }
    __syncthreads();
    float* Wblk = W + (size_t)(jb * 64) * DD + jb * 64;
    for (int t = tid; t < 4096; t += 256)
      Wblk[(size_t)(t >> 6) * DD + (t & 63)] = Wd[(t >> 6) * 68 + (t & 63)];
  }
}

// 64x64 NN GEMM tile on caller LDS (stride 68): Cd = sgn * A[:,k0:k1] * B[k0:k1,:]
__device__ __forceinline__ void nn64_sh(float* As, float* Bs,
    const float* __restrict__ A, int lda, const float* __restrict__ B, int ldb,
    float* __restrict__ Cd, int ldc, int k0, int k1, float sgn) {
  int tid = threadIdx.x, tr = tid >> 4, tc = tid & 15;
  float acc[4][4] = {};
  for (int kc = k0; kc < k1; kc += 64) {
    #pragma unroll
    for (int p = 0; p < 4; p++) {
      int f4 = tid + 256 * p;
      int row = f4 >> 4, c4 = f4 & 15;
      *(float4*)&As[row * 68 + c4 * 4] = *(const float4*)(A + (size_t)row * lda + kc + c4 * 4);
      *(float4*)&Bs[row * 68 + c4 * 4] = *(const float4*)(B + (size_t)(kc + row) * ldb + c4 * 4);
    }
    __syncthreads();
    #pragma unroll
    for (int kk = 0; kk < 64; kk++) {
      float a[4];
      #pragma unroll
      for (int x = 0; x < 4; x++) a[x] = As[(tr * 4 + x) * 68 + kk];
      float4 bv = *(const float4*)&Bs[kk * 68 + tc * 4];
      float bb[4] = {bv.x, bv.y, bv.z, bv.w};
      #pragma unroll
      for (int x = 0; x < 4; x++)
        #pragma unroll
        for (int y = 0; y < 4; y++) acc[x][y] += a[x] * bb[y];
    }
    __syncthreads();
  }
  #pragma unroll
  for (int x = 0; x < 4; x++) {
    float4 v = make_float4(sgn * acc[x][0], sgn * acc[x][1],
                           sgn * acc[x][2], sgn * acc[x][3]);
    *(float4*)(Cd + (size_t)(tr * 4 + x) * ldc + tc * 4) = v;
  }
}

#define GBK 16
// ============ triT level 128 fused with xmu partials ============
__global__ __launch_bounds__(256) void k_triT128_xmu(const float* __restrict__ L,
    const float* __restrict__ W, float* __restrict__ T,
    const float* __restrict__ Xq, const float* __restrict__ Mu,
    float* __restrict__ xmup) {
  __shared__ float sh[2 * 64 * 68];
  int b = blockIdx.x, tid = threadIdx.x;
  if (b < 4) {              // triT, s=128: h=64, tiles=1
    int g = b, base = g * 128;
    const float* A = L + (size_t)(base + 64) * DD + base;
    const float* B = W + (size_t)base * DD + base;
    float* Cd = T + (size_t)g * 64 * 64;
    nn64_sh(sh, sh + 64 * 68, A, DD, B, DD, Cd, 64, 0, 64, 1.0f);
  } else {                  // xmu partials: 32 q-rows, split-K=4
    float* As = sh;               // stride 36, 16 rows
    float* Bs = sh + 16 * 36;     // stride 68, 16 rows
    int xb = b - 4;
    int bm = (xb & 63) * 32, kq = xb >> 6;
    int tr = tid >> 4, tc = tid & 15;
    float acc[2][4] = {};
    int k0s = kq * (DD / XKS), k0e = k0s + DD / XKS;
    for (int k0 = k0s; k0 < k0e; k0 += GBK) {
      if (tid < 128) {
        int row = tid >> 2, k4 = tid & 3;
        float4 v = *(const float4*)(Xq + (size_t)(bm + row) * DD + k0 + k4 * 4);
        As[(k4 * 4 + 0) * 36 + row] = v.x; As[(k4 * 4 + 1) * 36 + row] = v.y;
        As[(k4 * 4 + 2) * 36 + row] = v.z; As[(k4 * 4 + 3) * 36 + row] = v.w;
      }
      {
        int row = tid >> 2, k4 = tid & 3;
        float4 v = *(const float4*)(Mu + (size_t)row * DD + k0 + k4 * 4);
        Bs[(k4 * 4 + 0) * 68 + row] = v.x; Bs[(k4 * 4 + 1) * 68 + row] = v.y;
        Bs[(k4 * 4 + 2) * 68 + row] = v.z; Bs[(k4 * 4 + 3) * 68 + row] = v.w;
      }
      __syncthreads();
      #pragma unroll
      for (int kk = 0; kk < GBK; kk++) {
        float a[2] = {As[kk * 36 + tr * 2], As[kk * 36 + tr * 2 + 1]};
        float4 b0 = *(const float4*)&Bs[kk * 68 + tc * 4];
        float bb[4] = {b0.x, b0.y, b0.z, b0.w};
        #pragma unroll
        for (int x = 0; x < 2; x++)
          #pragma unroll
          for (int y = 0; y < 4; y++) acc[x][y] += a[x] * bb[y];
      }
      __syncthreads();
    }
    #pragma unroll
    for (int x = 0; x < 2; x++) {
      int q = bm + tr * 2 + x;
      float4 v = make_float4(acc[x][0], acc[x][1], acc[x][2], acc[x][3]);
      *(float4*)(xmup + ((size_t)kq * QNQ + q) * CNUM + tc * 4) = v;
    }
  }
}

// generic trinv doubling levels
__global__ __launch_bounds__(256) void k_triT(const float* __restrict__ L,
                                              const float* __restrict__ W,
                                              float* __restrict__ T, int s) {
  __shared__ float sh[2 * 64 * 68];
  int h = s >> 1, tiles = h >> 6, per = tiles * tiles;
  int g = blockIdx.x / per, rem = blockIdx.x % per;
  int ti = rem / tiles, tj = rem % tiles;
  int base = g * s;
  const float* A = L + (size_t)(base + h + ti * 64) * DD + base;
  const float* B = W + (size_t)base * DD + base + tj * 64;
  float* Cd = T + (size_t)g * h * h + (size_t)(ti * 64) * h + tj * 64;
  nn64_sh(sh, sh + 64 * 68, A, DD, B, DD, Cd, h, tj * 64, h, 1.0f);
}

__global__ __launch_bounds__(256) void k_triX(float* __restrict__ W,
                                              const float* __restrict__ T, int s) {
  __shared__ float sh[2 * 64 * 68];
  int h = s >> 1, tiles = h >> 6, per = tiles * tiles;
  int g = blockIdx.x / per, rem = blockIdx.x % per;
  int ti = rem / tiles, tj = rem % tiles;
  int base = g * s;
  const float* A = W + (size_t)(base + h + ti * 64) * DD + base + h;
  const float* B = T + (size_t)g * h * h + tj * 64;
  float* Cd = W + (size_t)(base + h + ti * 64) * DD + base + tj * 64;
  nn64_sh(sh, sh + 64 * 68, A, DD, B, h, Cd, DD, 0, (ti + 1) * 64, -1.0f);
}

// ============ F3: Y-GEMM (64x64, tri-skip) + wm; epilogue also writes P=[Yh|Yl] bf16 ============
__global__ __launch_bounds__(256) void f_y_wm(const float* __restrict__ Xq,
    const float* __restrict__ Xs, const float* __restrict__ Mu,
    const float* __restrict__ W, const float* __restrict__ m,
    float* __restrict__ Y, unsigned short* __restrict__ Pm,
    float* __restrict__ wm) {
  __shared__ float As[GBK][68];
  __shared__ float Bs[GBK][68];
  int b = blockIdx.x, tid = threadIdx.x;
  if (b < 392) {            // Y = [Xq; Xs; mu] @ W^T; 49 m-tiles x 8 n-tiles
    int mt = b >> 3, nt = b & 7;
    int bm = mt * 64, bn = nt * 64;
    const float* A; int aOff;
    if (bm < QNQ)             { A = Xq; aOff = bm; }
    else if (bm < QNQ + NSUP) { A = Xs; aOff = bm - QNQ; }
    else                      { A = Mu; aOff = bm - QNQ - NSUP; }
    int tr = tid >> 4, tc = tid & 15;
    float acc[4][4] = {};
    int kend = bn + 64;     // W lower-triangular
    for (int k0 = 0; k0 < kend; k0 += GBK) {
      int row = tid >> 2, k4 = tid & 3;
      float4 v = *(const float4*)(A + (size_t)(aOff + row) * DD + k0 + k4 * 4);
      As[k4 * 4 + 0][row] = v.x; As[k4 * 4 + 1][row] = v.y;
      As[k4 * 4 + 2][row] = v.z; As[k4 * 4 + 3][row] = v.w;
      float4 w = *(const float4*)(W + (size_t)(bn + row) * DD + k0 + k4 * 4);
      Bs[k4 * 4 + 0][row] = w.x; Bs[k4 * 4 + 1][row] = w.y;
      Bs[k4 * 4 + 2][row] = w.z; Bs[k4 * 4 + 3][row] = w.w;
      __syncthreads();
      #pragma unroll
      for (int kk = 0; kk < GBK; kk++) {
        float4 a0 = *(const float4*)&As[kk][tr * 4];
        float4 b0 = *(const float4*)&Bs[kk][tc * 4];
        float a[4] = {a0.x, a0.y, a0.z, a0.w};
        float bb[4] = {b0.x, b0.y, b0.z, b0.w};
        #pragma unroll
        for (int x = 0; x < 4; x++)
          #pragma unroll
          for (int y = 0; y < 4; y++) acc[x][y] += a[x] * bb[y];
      }
      __syncthreads();
    }
    #pragma unroll
    for (int x = 0; x < 4; x++) {
      int row = bm + tr * 4 + x;
      float4 v = make_float4(acc[x][0], acc[x][1], acc[x][2], acc[x][3]);
      *(float4*)(Y + (size_t)row * DD + bn + tc * 4) = v;
      // bf16 hi/lo split for the MFMA Rg path
      ushort4 hi, lo;
      hi.x = f2bf(v.x); lo.x = f2bf(v.x - bf2f(hi.x));
      hi.y = f2bf(v.y); lo.y = f2bf(v.y - bf2f(hi.y));
      hi.z = f2bf(v.z); lo.z = f2bf(v.z - bf2f(hi.z));
      hi.w = f2bf(v.w); lo.w = f2bf(v.w - bf2f(hi.w));
      *(ushort4*)(Pm + (size_t)row * 1024 + bn + tc * 4) = hi;
      *(ushort4*)(Pm + (size_t)row * 1024 + 512 + bn + tc * 4) = lo;
    }
  } else {                  // wm[row] = W[row,:] . m  (4 rows/block)
    int wave = tid >> 6, lane = tid & 63;
    int row = (b - 392) * 4 + wave;
    float s = 0.0f;
    for (int j = lane; j < DD; j += 64) s += W[(size_t)row * DD + j] * m[j];
    for (int off = 32; off > 0; off >>= 1) s += __shfl_down(s, off);
    if (lane == 0) wm[row] = s;
  }
}

// fused: blocks 0..511 compute u[j]; block 512 computes SM consts
__global__ __launch_bounds__(256) void k_uB(const float* W, const float* L,
                                            const float* wm, float* u, float* cst) {
  __shared__ float red[256];
  __shared__ float red2[256];
  int b = blockIdx.x, tid = threadIdx.x;
  if (b < DD) {
    float s = 0.0f;
    for (int i = tid; i < DD; i += 256) s += W[(size_t)i * DD + b] * wm[i];
    red[tid] = s;
    __syncthreads();
    for (int off = 128; off > 0; off >>= 1) {
      if (tid < off) red[tid] += red[tid + off];
      __syncthreads();
    }
    if (tid == 0) u[b] = red[0];
  } else {
    float a = 0.0f, l = 0.0f;
    for (int t = tid; t < DD; t += 256) {
      float w = wm[t]; a += w * w;
      l += logf(fabsf(L[(size_t)t * DD + t]));
    }
    red[tid] = a; red2[tid] = l;
    __syncthreads();
    for (int off = 128; off > 0; off >>= 1) {
      if (tid < off) { red[tid] += red[tid + off]; red2[tid] += red2[tid + off]; }
      __syncthreads();
    }
    if (tid == 0) {
      float kap = cst[0], ss = red[0];
      cst[10] = kap / (1.0f + kap * ss);
      cst[11] = 2.0f * red2[0] + logf(1.0f + kap * ss);
    }
  }
}

// ============ F5: Rg via bf16-split MFMA, LDS-staged (canonical §5 structure) ============
// Pass h=0: Rg  = P . P^T          (= ah*bh + al*bl)
// Pass h=1: Rg2 = P . P(k^512)^T   (= ah*bl + al*bh)
// Sum (in k_logits) = exact (ah+al)(bh+bl).
#define PSTR 80   // LDS row stride in bf16 (160B: 16B-aligned b128 reads, modest conflicts)
__global__ __launch_bounds__(256) void f_z_rg(const unsigned short* __restrict__ Pm,
    const float* __restrict__ Y, const int* __restrict__ rowmap,
    const float* __restrict__ Xq, const float* __restrict__ u,
    const float* __restrict__ cst,
    float* __restrict__ Rg, float* __restrict__ Rg2,
    float* __restrict__ z, float* __restrict__ qn, float* __restrict__ qB) {
  __shared__ unsigned short Ash[64 * PSTR];   // 10.2 KB
  __shared__ unsigned short Bsh[64 * PSTR];   // 10.2 KB
  int b = blockIdx.x, tid = threadIdx.x;
  if (b < 1088) {           // 17 m-tiles x 32 n-tiles x 2 passes, 64x64 out
    int half = b / 544, rem = b % 544;
    int bm = (rem >> 5) * 64, bn = (rem & 31) * 64;
    float* out = half ? Rg2 : Rg;
    int kxor = half ? 512 : 0;
    int lane = tid & 63, wave = tid >> 6;
    int wr = wave >> 1, wc = wave & 1;    // 2x2 waves -> 32x32 each
    int mrow = lane & 15, q = lane >> 4;  // A/B frag: row/col = lane&15, kgroup = lane>>4
    // staging rows for this thread (2 per thread: idx = tid + 256*p)
    int srowA[2];
    #pragma unroll
    for (int p = 0; p < 2; p++) srowA[p] = rowmap[bm + ((tid + 256 * p) >> 3)];
    f32x4 acc00 = {}, acc01 = {}, acc10 = {}, acc11 = {};
    for (int it = 0; it < 16; it++) {
      int kc = it * 64;
      int kcB = kc ^ kxor;
      #pragma unroll
      for (int p = 0; p < 2; p++) {
        int idx = tid + 256 * p;
        int row = idx >> 3, c8 = idx & 7;
        short8 va = *(const short8*)(Pm + (size_t)srowA[p] * 1024 + kc + c8 * 8);
        *(short8*)&Ash[row * PSTR + c8 * 8] = va;
        short8 vb = *(const short8*)(Pm + (size_t)(bn + row) * 1024 + kcB + c8 * 8);
        *(short8*)&Bsh[row * PSTR + c8 * 8] = vb;
      }
      __syncthreads();
      #pragma unroll
      for (int ks = 0; ks < 2; ks++) {
        int ko = ks * 32 + q * 8;
        short8 a0 = *(const short8*)&Ash[(wr * 32 + mrow) * PSTR + ko];
        short8 a1 = *(const short8*)&Ash[(wr * 32 + 16 + mrow) * PSTR + ko];
        short8 b0 = *(const short8*)&Bsh[(wc * 32 + mrow) * PSTR + ko];
        short8 b1 = *(const short8*)&Bsh[(wc * 32 + 16 + mrow) * PSTR + ko];
        acc00 = __builtin_amdgcn_mfma_f32_16x16x32_bf16(a0, b0, acc00, 0, 0, 0);
        acc01 = __builtin_amdgcn_mfma_f32_16x16x32_bf16(a0, b1, acc01, 0, 0, 0);
        acc10 = __builtin_amdgcn_mfma_f32_16x16x32_bf16(a1, b0, acc10, 0, 0, 0);
        acc11 = __builtin_amdgcn_mfma_f32_16x16x32_bf16(a1, b1, acc11, 0, 0, 0);
      }
      __syncthreads();
    }
    // C/D layout: row = (lane>>4)*4 + r, col = lane&15
    #pragma unroll
    for (int r = 0; r < 4; r++) {
      int row0 = bm + wr * 32 + q * 4 + r;
      int row1 = row0 + 16;
      int col0 = bn + wc * 32 + mrow;
      out[(size_t)row0 * QNQ + col0]      = acc00[r];
      out[(size_t)row0 * QNQ + col0 + 16] = acc01[r];
      out[(size_t)row1 * QNQ + col0]      = acc10[r];
      out[(size_t)row1 * QNQ + col0 + 16] = acc11[r];
    }
  } else {                  // query rows: z, qn, qB (4 rows/block)
    int wave = tid >> 6, lane = tid & 63;
    int row = (b - 1088) * 4 + wave;
    const float* src = Xq + (size_t)row * DD;
    const float* yr = Y + (size_t)row * DD;
    float s = 0.0f, s1 = 0.0f, s2 = 0.0f;
    for (int j4 = lane; j4 < 128; j4 += 64) {
      float4 v = *(const float4*)(src + j4 * 4);
      float4 uu = *(const float4*)(u + j4 * 4);
      s += v.x * uu.x + v.y * uu.y + v.z * uu.z + v.w * uu.w;
      s1 += v.x * v.x + v.y * v.y + v.z * v.z + v.w * v.w;
      float4 yv = *(const float4*)(yr + j4 * 4);
      s2 += yv.x * yv.x + yv.y * yv.y + yv.z * yv.z + yv.w * yv.w;
    }
    for (int off = 32; off > 0; off >>= 1) {
      s += __shfl_down(s, off);
      s1 += __shfl_down(s1, off);
      s2 += __shfl_down(s2, off);
    }
    if (lane == 0) {
      z[row] = s;
      qn[row] = s1;
      qB[row] = s2 - cst[10] * s * s;
    }
  }
}

// ============ F6: per-class Gram (zs = Y.wm in-kernel) + GJ inverse + bias ============
#define YSTRIDE 516
__global__ __launch_bounds__(256) void k_gramminv(const float* Y, const float* wm,
    const int* rowmap, const float* cst, float* zg, float* Vmu, float* muBmu,
    float* Minv, float* bias) {
  __shared__ float Ys[17 * YSTRIDE];
  __shared__ float zs[17];
  __shared__ float aug[17][35];
  __shared__ float colk[17];
  __shared__ int pivrow;
  __shared__ float detacc;
  int c = blockIdx.x, tid = threadIdx.x;
  for (int t = tid; t < 17 * 128; t += 256) {
    int r = t >> 7, col = t & 127;
    *(float4*)&Ys[r * YSTRIDE + col * 4] =
        *(const float4*)(Y + (size_t)rowmap[c * 17 + r] * DD + col * 4);
  }
  __syncthreads();
  {
    int wave = tid >> 6, lane = tid & 63;
    for (int a = wave; a < 17; a += 4) {
      float s = 0.0f;
      for (int j = lane; j < DD; j += 64) s += Ys[a * YSTRIDE + j] * wm[j];
      for (int off = 32; off > 0; off >>= 1) s += __shfl_down(s, off);
      if (lane == 0) zs[a] = s;
    }
  }
  __syncthreads();
  float csm = cst[10];
  for (int e = tid; e < 289; e += 256) {
    int a = e / 17, bb = e % 17;
    const float* ra = &Ys[a * YSTRIDE];
    const float* rb = &Ys[bb * YSTRIDE];
    float s = 0.0f;
    for (int k = 0; k < 128; k++) {
      float4 va = *(const float4*)&ra[k * 4];
      float4 vb = *(const float4*)&rb[k * 4];
      s += va.x * vb.x + va.y * vb.y + va.z * vb.z + va.w * vb.w;
    }
    float g = s - csm * zs[a] * zs[bb];
    if (a == bb) g += (a < 16) ? 1.0f : cst[9];
    aug[a][bb] = g;
    aug[a][17 + bb] = (a == bb) ? 1.0f : 0.0f;
  }
  __syncthreads();
  if (tid < 17) {
    float gv = aug[tid][16];
    if (tid == 16) gv -= cst[9];
    Vmu[c * 17 + tid] = gv;
    if (tid == 16) muBmu[c] = gv;
    zg[c * 17 + tid] = zs[tid];
  }
  if (tid == 0) detacc = 0.0f;
  __syncthreads();
  for (int k = 0; k < 17; k++) {
    if (tid == 0) {
      int p = k; float best = fabsf(aug[k][k]);
      for (int r = k + 1; r < 17; r++) {
        float v = fabsf(aug[r][k]);
        if (v > best) { best = v; p = r; }
      }
      pivrow = p;
    }
    __syncthreads();
    int p = pivrow;
    if (p != k) {
      for (int cc = tid; cc < 34; cc += 256) {
        float tmp = aug[k][cc]; aug[k][cc] = aug[p][cc]; aug[p][cc] = tmp;
      }
    }
    __syncthreads();
    if (tid == 0) detacc += logf(fabsf(aug[k][k]));
    if (tid < 17) colk[tid] = aug[tid][k];
    __syncthreads();
    float invp = 1.0f / aug[k][k];
    for (int cc = tid; cc < 34; cc += 256) aug[k][cc] *= invp;
    __syncthreads();
    for (int t = tid; t < 17 * 34; t += 256) {
      int r = t / 34, cc = t % 34;
      if (r != k) aug[r][cc] -= colk[r] * aug[k][cc];
    }
    __syncthreads();
  }
  for (int t = tid; t < 289; t += 256) Minv[(size_t)c * 289 + t] = aug[t / 17][17 + t % 17];
  if (tid == 0) {
    float slog = logf(fabsf(cst[5])) + detacc;
    float logdetSigma = cst[8] + cst[11] + slog;
    bias[c] = cst[4] - 0.5f * logdetSigma;
  }
}

// final epilogue: Woodbury-corrected Mahalanobis -> logits[q,c]
__global__ __launch_bounds__(256) void k_logits(const float* __restrict__ Rg,
    const float* __restrict__ Rg2, const float* z, const float* zg,
    const float* Vmu, const float* muBmu, const float* mun, const float* qB,
    const float* qn, const float* xmup, const float* Minv, const float* bias,
    const float* cst, float* out) {
  __shared__ float Ms[289], Vs[17], Zs[17];
  int c = blockIdx.y;
  int q = blockIdx.x * 256 + threadIdx.x;
  for (int t = threadIdx.x; t < 289; t += 256) Ms[t] = Minv[(size_t)c * 289 + t];
  if (threadIdx.x < 17) {
    Vs[threadIdx.x] = Vmu[c * 17 + threadIdx.x];
    Zs[threadIdx.x] = zg[c * 17 + threadIdx.x];
  }
  __syncthreads();
  float csm = cst[10], scale = cst[1], common = cst[2], coef = cst[3];
  float zq = z[q];
  float r[17];
  float xBmu = 0.0f;
  for (int a = 0; a < 17; a++) {
    size_t off = (size_t)(c * 17 + a) * QNQ + q;
    float raw = Rg[off] + Rg2[off] - csm * Zs[a] * zq;
    if (a == 16) xBmu = raw;
    r[a] = raw - Vs[a];
  }
  float quadB = qB[q] - 2.0f * xBmu + muBmu[c];
  float corr = 0.0f;
  for (int a = 0; a < 17; a++) {
    float e = 0.0f;
    for (int bb = 0; bb < 17; bb++) e += Ms[a * 17 + bb] * r[bb];
    corr += r[a] * e;
  }
  float distB = (quadB - corr) / scale;
  float xm = 0.0f;
  #pragma unroll
  for (int p = 0; p < XKS; p++)
    xm += xmup[((size_t)p * QNQ + q) * CNUM + c];
  float dn = qn[q] - 2.0f * xm + mun[c];
  float dist = (1.0f - REGP) * distB + REGP * dn;
  out[(size_t)q * CNUM + c] = bias[c] - coef * log1pf(dist / common);
}

// ---------------- host ----------------
extern "C" void kernel_launch(void* const* d_in, const int* in_sizes, int n_in,
                              void* d_out, int out_size, void* d_ws, size_t ws_size,
                              hipStream_t stream) {
  const float* Xs    = (const float*)d_in[0];
  const int*   labels= (const int*)d_in[1];
  const float* Xq    = (const float*)d_in[2];
  const float* m     = (const float*)d_in[3];
  const float* kappa = (const float*)d_in[4];
  const float* nu    = (const float*)d_in[5];
  const float* tdiag = (const float*)d_in[6];
  const float* tlow  = (const float*)d_in[7];
  float* ws = (float*)d_ws;
  float* L    = ws + OFF_L;
  float* W    = ws + OFF_W;
  float* mu   = ws + OFF_MU;
  float* Y    = ws + OFF_Y;
  float* z    = ws + OFF_Z;
  float* wm   = ws + OFF_WM;
  float* u    = ws + OFF_U;
  float* cst  = ws + OFF_CONST;
  int*   idx  = (int*)(ws + OFF_IDX);
  int*   rmap = (int*)(ws + OFF_RMAP);
  float* zg   = ws + OFF_ZG;
  float* Vmu  = ws + OFF_VMU;
  float* muBmu= ws + OFF_MUBMU;
  float* mun  = ws + OFF_MUN;
  float* Minv = ws + OFF_MINV;
  float* bias = ws + OFF_BIAS;
  float* qB   = ws + OFF_QB;
  float* qn   = ws + OFF_QNRM;
  float* xmup = ws + OFF_XMU;
  float* Rg   = ws + OFF_RG;
  float* Rg2  = ws + OFF_RG2;
  unsigned short* P = (unsigned short*)(ws + OFF_P);
  float* Ttmp = ws + OFF_RG;       // trinv scratch, reused (Rg written later)
  float* out  = (float*)d_out;

  // F1: L/W init + consts + classidx + mu/mun + diag inverses (self-sufficient ranges)
  f_init<<<1161, 256, 0, stream>>>(tdiag, tlow, kappa, nu, labels, Xs, m,
                                   L, W, cst, idx, rmap, mu, mun);
  // trinv recursive doubling; level-128 T fused with xmu partials
  k_triT128_xmu<<<260, 256, 0, stream>>>(L, W, Ttmp, Xq, mu, xmup);
  k_triX<<<4, 256, 0, stream>>>(W, Ttmp, 128);
  k_triT<<<8, 256, 0, stream>>>(L, W, Ttmp, 256);
  k_triX<<<8, 256, 0, stream>>>(W, Ttmp, 256);
  k_triT<<<16, 256, 0, stream>>>(L, W, Ttmp, 512);
  k_triX<<<16, 256, 0, stream>>>(W, Ttmp, 512);
  // Y GEMM (64x64, tri-skip) + wm; also emits P = [Yh|Yl] bf16
  f_y_wm<<<520, 256, 0, stream>>>(Xq, Xs, mu, W, m, Y, P, wm);
  // u = W^T wm + SM consts
  k_uB<<<513, 256, 0, stream>>>(W, L, wm, u, cst);
  // Rg via 2-pass bf16-split MFMA (LDS-staged) + query z/qn/qB
  f_z_rg<<<1088 + 512, 256, 0, stream>>>(P, Y, rmap, Xq, u, cst, Rg, Rg2, z, qn, qB);
  // Gram (zs = Y.wm) + 17x17 inverse + bias
  k_gramminv<<<64, 256, 0, stream>>>(Y, wm, rmap, cst, zg, Vmu, muBmu, Minv, bias);
  k_logits<<<dim3(QNQ / 256, CNUM), 256, 0, stream>>>(Rg, Rg2, z, zg, Vmu, muBmu,
                                                      mun, qB, qn, xmup, Minv, bias,
                                                      cst, out);
  (void)in_sizes; (void)n_in; (void)out_size; (void)ws_size;
}

// Round 13
// 247.015 us; speedup vs baseline: 1.3000x; 1.0866x over previous
//
#include <hip/hip_runtime.h>
#include <math.h>

// Problem dims (fixed by setup_inputs)
#define DD    512
#define CNUM  64
#define SHOTS 16
#define NSUP  1024
#define QNQ   2048
#define REGP  0.1f
#define XKS   4      // xmu split-K parts

typedef __attribute__((ext_vector_type(8))) short short8;   // 8 bf16 = 4 VGPRs
typedef __attribute__((ext_vector_type(4))) float f32x4;

// bf16 round-to-nearest-even, raw bits
__device__ __forceinline__ unsigned short f2bf(float f) {
  unsigned int u = __float_as_uint(f);
  unsigned int r = (u + 0x7fffu + ((u >> 16) & 1u)) >> 16;
  return (unsigned short)r;
}
__device__ __forceinline__ float bf2f(unsigned short h) {
  return __uint_as_float((unsigned int)h << 16);
}

// ---------------- workspace layout (in floats) ----------------
static constexpr size_t OFF_L     = 0;                       // 512*512
static constexpr size_t OFF_W     = OFF_L     + 512*512;     // 512*512
static constexpr size_t OFF_MU    = OFF_W     + 512*512;     // 64*512
static constexpr size_t OFF_Y     = OFF_MU    + 64*512;      // 3136*512
static constexpr size_t OFF_Z     = OFF_Y     + 3136*512;    // 3136
static constexpr size_t OFF_WM    = OFF_Z     + 3136;        // 512
static constexpr size_t OFF_U     = OFF_WM    + 512;         // 512
static constexpr size_t OFF_CONST = OFF_U     + 512;         // 16
static constexpr size_t OFF_IDX   = OFF_CONST + 16;          // 1024 ints
static constexpr size_t OFF_RMAP  = OFF_IDX   + 1024;        // 1088 ints
static constexpr size_t OFF_ZG    = OFF_RMAP  + 1088;        // 1088
static constexpr size_t OFF_VMU   = OFF_ZG    + 1088;        // 1088
static constexpr size_t OFF_MUBMU = OFF_VMU   + 1088;        // 64
static constexpr size_t OFF_MUN   = OFF_MUBMU + 64;          // 64
static constexpr size_t OFF_MINV  = OFF_MUN   + 64;          // 64*289
static constexpr size_t OFF_BIAS  = OFF_MINV  + 64*289;      // 64
static constexpr size_t OFF_QB    = OFF_BIAS  + 64;          // 2048
static constexpr size_t OFF_QNRM  = OFF_QB    + 2048;        // 2048
static constexpr size_t OFF_XMU   = OFF_QNRM  + 2048;        // XKS*2048*64
static constexpr size_t OFF_RG    = OFF_XMU   + (size_t)XKS*2048*64; // 1088*2048 (also trinv T-scratch)
static constexpr size_t OFF_P     = OFF_RG    + 1088*2048;   // 3136*1024 bf16 (Y split)
static constexpr size_t OFF_PX    = OFF_P     + 3136*512;    // 3136*1024 bf16 (X split)
static constexpr size_t OFF_PW    = OFF_PX    + 3136*512;    // 512*1024 bf16 (W split)

// consts: 0 kap, 1 scale, 2 common, 3 coef, 4 bias0, 5 jlast,
// 6 cmu_m, 7 cmu_x, 8 D*log(scale), 9 Jinv_last, 10 c_sm, 11 logdetB

// ============ F1: L/W/PW init + consts + classidx + mu/mun(+PX) + diag-inv(+PW) + PX(X) ============
__global__ __launch_bounds__(256) void f_init(const float* tdiag, const float* tlow,
    const float* kappa, const float* nu, const int* labels, const float* Xs,
    const float* Xq, const float* m, float* L, float* W, float* cst, int* idx,
    int* rowmap, float* mu, float* mun,
    unsigned short* PX, unsigned short* PW) {
  __shared__ float sh[2 * 64 * 68];   // 34.8 KB union
  __shared__ int sidx[SHOTS];
  int b = blockIdx.x, tid = threadIdx.x;
  if (b < 1024) {
    int t = b * 256 + tid;
    int i = t >> 9, j = t & 511;
    L[t] = (i == j) ? fabsf(tdiag[i]) : (i > j ? tlow[t] : 0.0f);
    if ((i >> 6) < (j >> 6)) {          // strict-upper 64-blocks: zero W and PW
      W[t] = 0.0f;
      PW[(size_t)i * 1024 + j] = 0;
      PW[(size_t)i * 1024 + 512 + j] = 0;
    }
  } else if (b == 1024) {
    if (tid == 0) {
      float kap = fabsf(kappa[0]) + 1e-6f;
      float nu_ = fmaxf(nu[0], (float)(DD - 1) + 1e-6f);
      float common = nu_ + (float)SHOTS + 1.0f - (float)DD;
      float scale = (kap + SHOTS + 1.0f) / ((nu_ + SHOTS - DD + 1.0f) * (kap + SHOTS));
      cst[0] = kap;
      cst[1] = scale;
      cst[2] = common;
      cst[3] = 0.5f * (common + DD);
      cst[4] = lgammaf(0.5f * (common + DD)) - lgammaf(0.5f * common)
               - 0.5f * (float)DD * logf(common);
      cst[5] = -(kap + SHOTS);
      cst[6] = kap / (kap + SHOTS);
      cst[7] = 1.0f / (kap + SHOTS);
      cst[8] = (float)DD * logf(scale);
      cst[9] = -1.0f / (kap + SHOTS);
    }
  } else if (b < 1089) {
    int c = b - 1025;
    if (tid < 64) {
      int lane = tid, cnt = 0;
      for (int i0 = 0; i0 < NSUP; i0 += 64) {
        int lab = labels[i0 + lane];
        unsigned long long mm = __ballot(lab == c);
        if (lab == c) {
          int pos = cnt + __popcll(mm & ((1ull << lane) - 1ull));
          if (pos < SHOTS) idx[c * SHOTS + pos] = i0 + lane;
        }
        cnt += __popcll(mm);
      }
    }
    __syncthreads();
    if (tid < 17)
      rowmap[c * 17 + tid] = (tid < SHOTS) ? (QNQ + idx[c * SHOTS + tid])
                                           : (QNQ + NSUP + c);
  } else if (b < 1153) {
    // mu/mun with locally re-derived idx; also emit PX for mu rows
    int c = b - 1089;
    if (tid < 64) {
      int lane = tid, cnt = 0;
      for (int i0 = 0; i0 < NSUP; i0 += 64) {
        int lab = labels[i0 + lane];
        unsigned long long mm = __ballot(lab == c);
        if (lab == c) {
          int pos = cnt + __popcll(mm & ((1ull << lane) - 1ull));
          if (pos < SHOTS) sidx[pos] = i0 + lane;
        }
        cnt += __popcll(mm);
      }
    }
    __syncthreads();
    float kap = fabsf(kappa[0]) + 1e-6f;
    float cm = kap / (kap + SHOTS), cx = 1.0f / (kap + SHOTS);
    float* red = sh;
    float acc = 0.0f;
    size_t prow = (size_t)(3072 + c) * 1024;
    for (int d = tid; d < DD; d += 256) {
      float s = 0.0f;
      for (int sh_ = 0; sh_ < SHOTS; sh_++)
        s += Xs[(size_t)sidx[sh_] * DD + d];
      float v = cm * m[d] + cx * s;
      mu[(size_t)c * DD + d] = v;
      unsigned short h = f2bf(v), l = f2bf(v - bf2f(h));
      PX[prow + d] = h;
      PX[prow + 512 + d] = l;
      acc += v * v;
    }
    red[tid] = acc;
    __syncthreads();
    for (int off = 128; off > 0; off >>= 1) {
      if (tid < off) red[tid] += red[tid + off];
      __syncthreads();
    }
    if (tid == 0) mun[c] = red[0];
  } else if (b < 1161) {
    // diag 64x64 inverse + PW emit
    int jb = b - 1153;
    float* Ld = sh;             // [64][68]
    float* Wd = sh + 64 * 68;   // [64][68]
    for (int t = tid; t < 4096; t += 256) {
      int r = t >> 6, c = t & 63;
      int gr = jb * 64 + r;
      float v = (r == c) ? fabsf(tdiag[gr])
              : (r > c ? tlow[(size_t)gr * DD + jb * 64 + c] : 0.0f);
      Ld[r * 68 + c] = v;
    }
    __syncthreads();
    if (tid < 64) {
      for (int i = 0; i < 64; i++) {
        float w = (i == tid) ? 1.0f : 0.0f;
        for (int k = 0; k < i; k++) w -= Ld[i * 68 + k] * Wd[k * 68 + tid];
        Wd[i * 68 + tid] = w / Ld[i * 68 + i];
      }
    }
    __syncthreads();
    float* Wblk = W + (size_t)(jb * 64) * DD + jb * 64;
    for (int t = tid; t < 4096; t += 256) {
      int r = t >> 6, c = t & 63;
      float v = Wd[r * 68 + c];
      Wblk[(size_t)r * DD + c] = v;
      unsigned short h = f2bf(v), l = f2bf(v - bf2f(h));
      size_t prow = (size_t)(jb * 64 + r) * 1024 + jb * 64 + c;
      PW[prow] = h;
      PW[prow + 512] = l;
    }
  } else {
    // PX for Xq/Xs rows: 4 rows per block
    int r0 = (b - 1161) * 4;
    int row = r0 + (tid >> 6), lane = tid & 63;
    const float* src = (row < QNQ) ? Xq + (size_t)row * DD
                                   : Xs + (size_t)(row - QNQ) * DD;
    size_t prow = (size_t)row * 1024;
    #pragma unroll
    for (int p = 0; p < 2; p++) {
      int col = lane * 8 + p * 4;
      float4 v = *(const float4*)(src + col);
      ushort4 hi, lo;
      hi.x = f2bf(v.x); lo.x = f2bf(v.x - bf2f(hi.x));
      hi.y = f2bf(v.y); lo.y = f2bf(v.y - bf2f(hi.y));
      hi.z = f2bf(v.z); lo.z = f2bf(v.z - bf2f(hi.z));
      hi.w = f2bf(v.w); lo.w = f2bf(v.w - bf2f(hi.w));
      *(ushort4*)(PX + prow + col) = hi;
      *(ushort4*)(PX + prow + 512 + col) = lo;
    }
  }
}

// 64x64 NN GEMM tile on caller LDS (stride 68): Cd = sgn * A[:,k0:k1] * B[k0:k1,:]
// If Pw != nullptr, also emit bf16 hi/lo split at PW[gr0+.., gc0+..].
__device__ __forceinline__ void nn64_sh(float* As, float* Bs,
    const float* __restrict__ A, int lda, const float* __restrict__ B, int ldb,
    float* __restrict__ Cd, int ldc, int k0, int k1, float sgn,
    unsigned short* __restrict__ Pw, int gr0, int gc0) {
  int tid = threadIdx.x, tr = tid >> 4, tc = tid & 15;
  float acc[4][4] = {};
  for (int kc = k0; kc < k1; kc += 64) {
    #pragma unroll
    for (int p = 0; p < 4; p++) {
      int f4 = tid + 256 * p;
      int row = f4 >> 4, c4 = f4 & 15;
      *(float4*)&As[row * 68 + c4 * 4] = *(const float4*)(A + (size_t)row * lda + kc + c4 * 4);
      *(float4*)&Bs[row * 68 + c4 * 4] = *(const float4*)(B + (size_t)(kc + row) * ldb + c4 * 4);
    }
    __syncthreads();
    #pragma unroll
    for (int kk = 0; kk < 64; kk++) {
      float a[4];
      #pragma unroll
      for (int x = 0; x < 4; x++) a[x] = As[(tr * 4 + x) * 68 + kk];
      float4 bv = *(const float4*)&Bs[kk * 68 + tc * 4];
      float bb[4] = {bv.x, bv.y, bv.z, bv.w};
      #pragma unroll
      for (int x = 0; x < 4; x++)
        #pragma unroll
        for (int y = 0; y < 4; y++) acc[x][y] += a[x] * bb[y];
    }
    __syncthreads();
  }
  #pragma unroll
  for (int x = 0; x < 4; x++) {
    float4 v = make_float4(sgn * acc[x][0], sgn * acc[x][1],
                           sgn * acc[x][2], sgn * acc[x][3]);
    *(float4*)(Cd + (size_t)(tr * 4 + x) * ldc + tc * 4) = v;
    if (Pw) {
      size_t prow = (size_t)(gr0 + tr * 4 + x) * 1024 + gc0 + tc * 4;
      float vv[4] = {v.x, v.y, v.z, v.w};
      #pragma unroll
      for (int y = 0; y < 4; y++) {
        unsigned short h = f2bf(vv[y]), l = f2bf(vv[y] - bf2f(h));
        Pw[prow + y] = h;
        Pw[prow + 512 + y] = l;
      }
    }
  }
}

#define GBK 16
// ============ triT level 128 fused with xmu partials ============
__global__ __launch_bounds__(256) void k_triT128_xmu(const float* __restrict__ L,
    const float* __restrict__ W, float* __restrict__ T,
    const float* __restrict__ Xq, const float* __restrict__ Mu,
    float* __restrict__ xmup) {
  __shared__ float sh[2 * 64 * 68];
  int b = blockIdx.x, tid = threadIdx.x;
  if (b < 4) {              // triT, s=128: h=64, tiles=1
    int g = b, base = g * 128;
    const float* A = L + (size_t)(base + 64) * DD + base;
    const float* B = W + (size_t)base * DD + base;
    float* Cd = T + (size_t)g * 64 * 64;
    nn64_sh(sh, sh + 64 * 68, A, DD, B, DD, Cd, 64, 0, 64, 1.0f, nullptr, 0, 0);
  } else {                  // xmu partials: 32 q-rows, split-K=4
    float* As = sh;               // stride 36, 16 rows
    float* Bs = sh + 16 * 36;     // stride 68, 16 rows
    int xb = b - 4;
    int bm = (xb & 63) * 32, kq = xb >> 6;
    int tr = tid >> 4, tc = tid & 15;
    float acc[2][4] = {};
    int k0s = kq * (DD / XKS), k0e = k0s + DD / XKS;
    for (int k0 = k0s; k0 < k0e; k0 += GBK) {
      if (tid < 128) {
        int row = tid >> 2, k4 = tid & 3;
        float4 v = *(const float4*)(Xq + (size_t)(bm + row) * DD + k0 + k4 * 4);
        As[(k4 * 4 + 0) * 36 + row] = v.x; As[(k4 * 4 + 1) * 36 + row] = v.y;
        As[(k4 * 4 + 2) * 36 + row] = v.z; As[(k4 * 4 + 3) * 36 + row] = v.w;
      }
      {
        int row = tid >> 2, k4 = tid & 3;
        float4 v = *(const float4*)(Mu + (size_t)row * DD + k0 + k4 * 4);
        Bs[(k4 * 4 + 0) * 68 + row] = v.x; Bs[(k4 * 4 + 1) * 68 + row] = v.y;
        Bs[(k4 * 4 + 2) * 68 + row] = v.z; Bs[(k4 * 4 + 3) * 68 + row] = v.w;
      }
      __syncthreads();
      #pragma unroll
      for (int kk = 0; kk < GBK; kk++) {
        float a[2] = {As[kk * 36 + tr * 2], As[kk * 36 + tr * 2 + 1]};
        float4 b0 = *(const float4*)&Bs[kk * 68 + tc * 4];
        float bb[4] = {b0.x, b0.y, b0.z, b0.w};
        #pragma unroll
        for (int x = 0; x < 2; x++)
          #pragma unroll
          for (int y = 0; y < 4; y++) acc[x][y] += a[x] * bb[y];
      }
      __syncthreads();
    }
    #pragma unroll
    for (int x = 0; x < 2; x++) {
      int q = bm + tr * 2 + x;
      float4 v = make_float4(acc[x][0], acc[x][1], acc[x][2], acc[x][3]);
      *(float4*)(xmup + ((size_t)kq * QNQ + q) * CNUM + tc * 4) = v;
    }
  }
}

// generic trinv doubling levels
__global__ __launch_bounds__(256) void k_triT(const float* __restrict__ L,
                                              const float* __restrict__ W,
                                              float* __restrict__ T, int s) {
  __shared__ float sh[2 * 64 * 68];
  int h = s >> 1, tiles = h >> 6, per = tiles * tiles;
  int g = blockIdx.x / per, rem = blockIdx.x % per;
  int ti = rem / tiles, tj = rem % tiles;
  int base = g * s;
  const float* A = L + (size_t)(base + h + ti * 64) * DD + base;
  const float* B = W + (size_t)base * DD + base + tj * 64;
  float* Cd = T + (size_t)g * h * h + (size_t)(ti * 64) * h + tj * 64;
  nn64_sh(sh, sh + 64 * 68, A, DD, B, DD, Cd, h, tj * 64, h, 1.0f, nullptr, 0, 0);
}

// triX also emits PW (the bf16 hi/lo of the W blocks it writes)
__global__ __launch_bounds__(256) void k_triX(float* __restrict__ W,
                                              const float* __restrict__ T, int s,
                                              unsigned short* __restrict__ PW) {
  __shared__ float sh[2 * 64 * 68];
  int h = s >> 1, tiles = h >> 6, per = tiles * tiles;
  int g = blockIdx.x / per, rem = blockIdx.x % per;
  int ti = rem / tiles, tj = rem % tiles;
  int base = g * s;
  const float* A = W + (size_t)(base + h + ti * 64) * DD + base + h;
  const float* B = T + (size_t)g * h * h + tj * 64;
  int gr0 = base + h + ti * 64, gc0 = base + tj * 64;
  float* Cd = W + (size_t)gr0 * DD + gc0;
  nn64_sh(sh, sh + 64 * 68, A, DD, B, h, Cd, DD, 0, (ti + 1) * 64, -1.0f, PW, gr0, gc0);
}

#define PSTR 80   // LDS row stride in bf16
// ============ F3: Y-GEMM via 4-combo bf16-split MFMA (tri-skip) + wm ============
// Y = (Xh+Xl)(Wh+Wl)^T : all four products accumulate into one fp32 MFMA acc (exact).
__global__ __launch_bounds__(256) void f_y_wm(const unsigned short* __restrict__ PX,
    const unsigned short* __restrict__ PW, const float* __restrict__ W,
    const float* __restrict__ m, float* __restrict__ Y,
    unsigned short* __restrict__ Pm, float* __restrict__ wm) {
  __shared__ unsigned short AshH[64 * PSTR];
  __shared__ unsigned short AshL[64 * PSTR];
  __shared__ unsigned short BshH[64 * PSTR];
  __shared__ unsigned short BshL[64 * PSTR];
  int b = blockIdx.x, tid = threadIdx.x;
  if (b < 392) {            // 49 m-tiles x 8 n-tiles, 64x64
    int mt = b >> 3, nt = b & 7;
    int bm = mt * 64, bn = nt * 64;
    int lane = tid & 63, wave = tid >> 6;
    int wr = wave >> 1, wc = wave & 1;
    int mrow = lane & 15, q = lane >> 4;
    f32x4 acc00 = {}, acc01 = {}, acc10 = {}, acc11 = {};
    int kchunks = nt + 1;   // W lower-triangular: k < bn+64
    for (int it = 0; it < kchunks; it++) {
      int kc = it * 64;
      #pragma unroll
      for (int p = 0; p < 2; p++) {
        int idx = tid + 256 * p;
        int row = idx >> 3, c8 = (idx & 7) * 8;
        *(short8*)&AshH[row * PSTR + c8] =
            *(const short8*)(PX + (size_t)(bm + row) * 1024 + kc + c8);
        *(short8*)&AshL[row * PSTR + c8] =
            *(const short8*)(PX + (size_t)(bm + row) * 1024 + 512 + kc + c8);
        *(short8*)&BshH[row * PSTR + c8] =
            *(const short8*)(PW + (size_t)(bn + row) * 1024 + kc + c8);
        *(short8*)&BshL[row * PSTR + c8] =
            *(const short8*)(PW + (size_t)(bn + row) * 1024 + 512 + kc + c8);
      }
      __syncthreads();
      #pragma unroll
      for (int ks = 0; ks < 2; ks++) {
        int ko = ks * 32 + q * 8;
        short8 ah0 = *(const short8*)&AshH[(wr * 32 + mrow) * PSTR + ko];
        short8 ah1 = *(const short8*)&AshH[(wr * 32 + 16 + mrow) * PSTR + ko];
        short8 al0 = *(const short8*)&AshL[(wr * 32 + mrow) * PSTR + ko];
        short8 al1 = *(const short8*)&AshL[(wr * 32 + 16 + mrow) * PSTR + ko];
        short8 bh0 = *(const short8*)&BshH[(wc * 32 + mrow) * PSTR + ko];
        short8 bh1 = *(const short8*)&BshH[(wc * 32 + 16 + mrow) * PSTR + ko];
        short8 bl0 = *(const short8*)&BshL[(wc * 32 + mrow) * PSTR + ko];
        short8 bl1 = *(const short8*)&BshL[(wc * 32 + 16 + mrow) * PSTR + ko];
        acc00 = __builtin_amdgcn_mfma_f32_16x16x32_bf16(ah0, bh0, acc00, 0, 0, 0);
        acc00 = __builtin_amdgcn_mfma_f32_16x16x32_bf16(ah0, bl0, acc00, 0, 0, 0);
        acc00 = __builtin_amdgcn_mfma_f32_16x16x32_bf16(al0, bh0, acc00, 0, 0, 0);
        acc00 = __builtin_amdgcn_mfma_f32_16x16x32_bf16(al0, bl0, acc00, 0, 0, 0);
        acc01 = __builtin_amdgcn_mfma_f32_16x16x32_bf16(ah0, bh1, acc01, 0, 0, 0);
        acc01 = __builtin_amdgcn_mfma_f32_16x16x32_bf16(ah0, bl1, acc01, 0, 0, 0);
        acc01 = __builtin_amdgcn_mfma_f32_16x16x32_bf16(al0, bh1, acc01, 0, 0, 0);
        acc01 = __builtin_amdgcn_mfma_f32_16x16x32_bf16(al0, bl1, acc01, 0, 0, 0);
        acc10 = __builtin_amdgcn_mfma_f32_16x16x32_bf16(ah1, bh0, acc10, 0, 0, 0);
        acc10 = __builtin_amdgcn_mfma_f32_16x16x32_bf16(ah1, bl0, acc10, 0, 0, 0);
        acc10 = __builtin_amdgcn_mfma_f32_16x16x32_bf16(al1, bh0, acc10, 0, 0, 0);
        acc10 = __builtin_amdgcn_mfma_f32_16x16x32_bf16(al1, bl0, acc10, 0, 0, 0);
        acc11 = __builtin_amdgcn_mfma_f32_16x16x32_bf16(ah1, bh1, acc11, 0, 0, 0);
        acc11 = __builtin_amdgcn_mfma_f32_16x16x32_bf16(ah1, bl1, acc11, 0, 0, 0);
        acc11 = __builtin_amdgcn_mfma_f32_16x16x32_bf16(al1, bh1, acc11, 0, 0, 0);
        acc11 = __builtin_amdgcn_mfma_f32_16x16x32_bf16(al1, bl1, acc11, 0, 0, 0);
      }
      __syncthreads();
    }
    // C/D layout: row = (lane>>4)*4 + r, col = lane&15
    #pragma unroll
    for (int r = 0; r < 4; r++) {
      int row0 = bm + wr * 32 + q * 4 + r;
      int row1 = row0 + 16;
      int col0 = bn + wc * 32 + mrow;
      float vv[4] = {acc00[r], acc01[r], acc10[r], acc11[r]};
      int rows[4] = {row0, row0, row1, row1};
      int cols[4] = {col0, col0 + 16, col0, col0 + 16};
      #pragma unroll
      for (int e = 0; e < 4; e++) {
        Y[(size_t)rows[e] * DD + cols[e]] = vv[e];
        unsigned short h = f2bf(vv[e]), l = f2bf(vv[e] - bf2f(h));
        Pm[(size_t)rows[e] * 1024 + cols[e]] = h;
        Pm[(size_t)rows[e] * 1024 + 512 + cols[e]] = l;
      }
    }
  } else {                  // wm[row] = W[row,:] . m  (4 rows/block)
    int wave = tid >> 6, lane = tid & 63;
    int row = (b - 392) * 4 + wave;
    float s = 0.0f;
    for (int j = lane; j < DD; j += 64) s += W[(size_t)row * DD + j] * m[j];
    for (int off = 32; off > 0; off >>= 1) s += __shfl_down(s, off);
    if (lane == 0) wm[row] = s;
  }
}

// fused: blocks 0..511 compute u[j]; block 512 computes SM consts
__global__ __launch_bounds__(256) void k_uB(const float* W, const float* L,
                                            const float* wm, float* u, float* cst) {
  __shared__ float red[256];
  __shared__ float red2[256];
  int b = blockIdx.x, tid = threadIdx.x;
  if (b < DD) {
    float s = 0.0f;
    for (int i = tid; i < DD; i += 256) s += W[(size_t)i * DD + b] * wm[i];
    red[tid] = s;
    __syncthreads();
    for (int off = 128; off > 0; off >>= 1) {
      if (tid < off) red[tid] += red[tid + off];
      __syncthreads();
    }
    if (tid == 0) u[b] = red[0];
  } else {
    float a = 0.0f, l = 0.0f;
    for (int t = tid; t < DD; t += 256) {
      float w = wm[t]; a += w * w;
      l += logf(fabsf(L[(size_t)t * DD + t]));
    }
    red[tid] = a; red2[tid] = l;
    __syncthreads();
    for (int off = 128; off > 0; off >>= 1) {
      if (tid < off) { red[tid] += red[tid + off]; red2[tid] += red2[tid + off]; }
      __syncthreads();
    }
    if (tid == 0) {
      float kap = cst[0], ss = red[0];
      cst[10] = kap / (1.0f + kap * ss);
      cst[11] = 2.0f * red2[0] + logf(1.0f + kap * ss);
    }
  }
}

// ============ F5: Rg via bf16-split MFMA, both passes fused per chunk, one buffer ============
// Rg = P . P^T + P . P(k^512)^T = exact (Yh+Yl)(Yh+Yl)^T
__global__ __launch_bounds__(256) void f_z_rg(const unsigned short* __restrict__ Pm,
    const float* __restrict__ Y, const int* __restrict__ rowmap,
    const float* __restrict__ Xq, const float* __restrict__ u,
    const float* __restrict__ cst,
    float* __restrict__ Rg,
    float* __restrict__ z, float* __restrict__ qn, float* __restrict__ qB) {
  __shared__ unsigned short Ash[64 * PSTR];   // 10.2 KB
  __shared__ unsigned short Bsh[64 * PSTR];   // pass-1 B
  __shared__ unsigned short Csh[64 * PSTR];   // pass-2 B (k^512)
  int b = blockIdx.x, tid = threadIdx.x;
  if (b < 544) {            // 17 m-tiles x 32 n-tiles, 64x64 out
    int bm = (b >> 5) * 64, bn = (b & 31) * 64;
    int lane = tid & 63, wave = tid >> 6;
    int wr = wave >> 1, wc = wave & 1;
    int mrow = lane & 15, q = lane >> 4;
    int srowA[2];
    #pragma unroll
    for (int p = 0; p < 2; p++) srowA[p] = rowmap[bm + ((tid + 256 * p) >> 3)];
    f32x4 acc00 = {}, acc01 = {}, acc10 = {}, acc11 = {};
    for (int it = 0; it < 16; it++) {
      int kc = it * 64;
      int kcX = kc ^ 512;
      #pragma unroll
      for (int p = 0; p < 2; p++) {
        int idx = tid + 256 * p;
        int row = idx >> 3, c8 = (idx & 7) * 8;
        *(short8*)&Ash[row * PSTR + c8] =
            *(const short8*)(Pm + (size_t)srowA[p] * 1024 + kc + c8);
        *(short8*)&Bsh[row * PSTR + c8] =
            *(const short8*)(Pm + (size_t)(bn + row) * 1024 + kc + c8);
        *(short8*)&Csh[row * PSTR + c8] =
            *(const short8*)(Pm + (size_t)(bn + row) * 1024 + kcX + c8);
      }
      __syncthreads();
      #pragma unroll
      for (int ks = 0; ks < 2; ks++) {
        int ko = ks * 32 + q * 8;
        short8 a0 = *(const short8*)&Ash[(wr * 32 + mrow) * PSTR + ko];
        short8 a1 = *(const short8*)&Ash[(wr * 32 + 16 + mrow) * PSTR + ko];
        short8 b0 = *(const short8*)&Bsh[(wc * 32 + mrow) * PSTR + ko];
        short8 b1 = *(const short8*)&Bsh[(wc * 32 + 16 + mrow) * PSTR + ko];
        short8 c0 = *(const short8*)&Csh[(wc * 32 + mrow) * PSTR + ko];
        short8 c1 = *(const short8*)&Csh[(wc * 32 + 16 + mrow) * PSTR + ko];
        acc00 = __builtin_amdgcn_mfma_f32_16x16x32_bf16(a0, b0, acc00, 0, 0, 0);
        acc01 = __builtin_amdgcn_mfma_f32_16x16x32_bf16(a0, b1, acc01, 0, 0, 0);
        acc10 = __builtin_amdgcn_mfma_f32_16x16x32_bf16(a1, b0, acc10, 0, 0, 0);
        acc11 = __builtin_amdgcn_mfma_f32_16x16x32_bf16(a1, b1, acc11, 0, 0, 0);
        acc00 = __builtin_amdgcn_mfma_f32_16x16x32_bf16(a0, c0, acc00, 0, 0, 0);
        acc01 = __builtin_amdgcn_mfma_f32_16x16x32_bf16(a0, c1, acc01, 0, 0, 0);
        acc10 = __builtin_amdgcn_mfma_f32_16x16x32_bf16(a1, c0, acc10, 0, 0, 0);
        acc11 = __builtin_amdgcn_mfma_f32_16x16x32_bf16(a1, c1, acc11, 0, 0, 0);
      }
      __syncthreads();
    }
    #pragma unroll
    for (int r = 0; r < 4; r++) {
      int row0 = bm + wr * 32 + q * 4 + r;
      int row1 = row0 + 16;
      int col0 = bn + wc * 32 + mrow;
      Rg[(size_t)row0 * QNQ + col0]      = acc00[r];
      Rg[(size_t)row0 * QNQ + col0 + 16] = acc01[r];
      Rg[(size_t)row1 * QNQ + col0]      = acc10[r];
      Rg[(size_t)row1 * QNQ + col0 + 16] = acc11[r];
    }
  } else {                  // query rows: z, qn, qB (4 rows/block)
    int wave = tid >> 6, lane = tid & 63;
    int row = (b - 544) * 4 + wave;
    const float* src = Xq + (size_t)row * DD;
    const float* yr = Y + (size_t)row * DD;
    float s = 0.0f, s1 = 0.0f, s2 = 0.0f;
    for (int j4 = lane; j4 < 128; j4 += 64) {
      float4 v = *(const float4*)(src + j4 * 4);
      float4 uu = *(const float4*)(u + j4 * 4);
      s += v.x * uu.x + v.y * uu.y + v.z * uu.z + v.w * uu.w;
      s1 += v.x * v.x + v.y * v.y + v.z * v.z + v.w * v.w;
      float4 yv = *(const float4*)(yr + j4 * 4);
      s2 += yv.x * yv.x + yv.y * yv.y + yv.z * yv.z + yv.w * yv.w;
    }
    for (int off = 32; off > 0; off >>= 1) {
      s += __shfl_down(s, off);
      s1 += __shfl_down(s1, off);
      s2 += __shfl_down(s2, off);
    }
    if (lane == 0) {
      z[row] = s;
      qn[row] = s1;
      qB[row] = s2 - cst[10] * s * s;
    }
  }
}

// ============ F6: per-class Gram (zs = Y.wm in-kernel) + GJ inverse + bias ============
#define YSTRIDE 516
__global__ __launch_bounds__(256) void k_gramminv(const float* Y, const float* wm,
    const int* rowmap, const float* cst, float* zg, float* Vmu, float* muBmu,
    float* Minv, float* bias) {
  __shared__ float Ys[17 * YSTRIDE];
  __shared__ float zs[17];
  __shared__ float aug[17][35];
  __shared__ float colk[17];
  __shared__ int pivrow;
  __shared__ float detacc;
  int c = blockIdx.x, tid = threadIdx.x;
  for (int t = tid; t < 17 * 128; t += 256) {
    int r = t >> 7, col = t & 127;
    *(float4*)&Ys[r * YSTRIDE + col * 4] =
        *(const float4*)(Y + (size_t)rowmap[c * 17 + r] * DD + col * 4);
  }
  __syncthreads();
  {
    int wave = tid >> 6, lane = tid & 63;
    for (int a = wave; a < 17; a += 4) {
      float s = 0.0f;
      for (int j = lane; j < DD; j += 64) s += Ys[a * YSTRIDE + j] * wm[j];
      for (int off = 32; off > 0; off >>= 1) s += __shfl_down(s, off);
      if (lane == 0) zs[a] = s;
    }
  }
  __syncthreads();
  float csm = cst[10];
  for (int e = tid; e < 289; e += 256) {
    int a = e / 17, bb = e % 17;
    const float* ra = &Ys[a * YSTRIDE];
    const float* rb = &Ys[bb * YSTRIDE];
    float s = 0.0f;
    for (int k = 0; k < 128; k++) {
      float4 va = *(const float4*)&ra[k * 4];
      float4 vb = *(const float4*)&rb[k * 4];
      s += va.x * vb.x + va.y * vb.y + va.z * vb.z + va.w * vb.w;
    }
    float g = s - csm * zs[a] * zs[bb];
    if (a == bb) g += (a < 16) ? 1.0f : cst[9];
    aug[a][bb] = g;
    aug[a][17 + bb] = (a == bb) ? 1.0f : 0.0f;
  }
  __syncthreads();
  if (tid < 17) {
    float gv = aug[tid][16];
    if (tid == 16) gv -= cst[9];
    Vmu[c * 17 + tid] = gv;
    if (tid == 16) muBmu[c] = gv;
    zg[c * 17 + tid] = zs[tid];
  }
  if (tid == 0) detacc = 0.0f;
  __syncthreads();
  for (int k = 0; k < 17; k++) {
    if (tid == 0) {
      int p = k; float best = fabsf(aug[k][k]);
      for (int r = k + 1; r < 17; r++) {
        float v = fabsf(aug[r][k]);
        if (v > best) { best = v; p = r; }
      }
      pivrow = p;
    }
    __syncthreads();
    int p = pivrow;
    if (p != k) {
      for (int cc = tid; cc < 34; cc += 256) {
        float tmp = aug[k][cc]; aug[k][cc] = aug[p][cc]; aug[p][cc] = tmp;
      }
    }
    __syncthreads();
    if (tid == 0) detacc += logf(fabsf(aug[k][k]));
    if (tid < 17) colk[tid] = aug[tid][k];
    __syncthreads();
    float invp = 1.0f / aug[k][k];
    for (int cc = tid; cc < 34; cc += 256) aug[k][cc] *= invp;
    __syncthreads();
    for (int t = tid; t < 17 * 34; t += 256) {
      int r = t / 34, cc = t % 34;
      if (r != k) aug[r][cc] -= colk[r] * aug[k][cc];
    }
    __syncthreads();
  }
  for (int t = tid; t < 289; t += 256) Minv[(size_t)c * 289 + t] = aug[t / 17][17 + t % 17];
  if (tid == 0) {
    float slog = logf(fabsf(cst[5])) + detacc;
    float logdetSigma = cst[8] + cst[11] + slog;
    bias[c] = cst[4] - 0.5f * logdetSigma;
  }
}

// final epilogue: Woodbury-corrected Mahalanobis -> logits[q,c]
__global__ __launch_bounds__(256) void k_logits(const float* __restrict__ Rg,
    const float* z, const float* zg,
    const float* Vmu, const float* muBmu, const float* mun, const float* qB,
    const float* qn, const float* xmup, const float* Minv, const float* bias,
    const float* cst, float* out) {
  __shared__ float Ms[289], Vs[17], Zs[17];
  int c = blockIdx.y;
  int q = blockIdx.x * 256 + threadIdx.x;
  for (int t = threadIdx.x; t < 289; t += 256) Ms[t] = Minv[(size_t)c * 289 + t];
  if (threadIdx.x < 17) {
    Vs[threadIdx.x] = Vmu[c * 17 + threadIdx.x];
    Zs[threadIdx.x] = zg[c * 17 + threadIdx.x];
  }
  __syncthreads();
  float csm = cst[10], scale = cst[1], common = cst[2], coef = cst[3];
  float zq = z[q];
  float r[17];
  float xBmu = 0.0f;
  for (int a = 0; a < 17; a++) {
    float raw = Rg[(size_t)(c * 17 + a) * QNQ + q] - csm * Zs[a] * zq;
    if (a == 16) xBmu = raw;
    r[a] = raw - Vs[a];
  }
  float quadB = qB[q] - 2.0f * xBmu + muBmu[c];
  float corr = 0.0f;
  for (int a = 0; a < 17; a++) {
    float e = 0.0f;
    for (int bb = 0; bb < 17; bb++) e += Ms[a * 17 + bb] * r[bb];
    corr += r[a] * e;
  }
  float distB = (quadB - corr) / scale;
  float xm = 0.0f;
  #pragma unroll
  for (int p = 0; p < XKS; p++)
    xm += xmup[((size_t)p * QNQ + q) * CNUM + c];
  float dn = qn[q] - 2.0f * xm + mun[c];
  float dist = (1.0f - REGP) * distB + REGP * dn;
  out[(size_t)q * CNUM + c] = bias[c] - coef * log1pf(dist / common);
}

// ---------------- host ----------------
extern "C" void kernel_launch(void* const* d_in, const int* in_sizes, int n_in,
                              void* d_out, int out_size, void* d_ws, size_t ws_size,
                              hipStream_t stream) {
  const float* Xs    = (const float*)d_in[0];
  const int*   labels= (const int*)d_in[1];
  const float* Xq    = (const float*)d_in[2];
  const float* m     = (const float*)d_in[3];
  const float* kappa = (const float*)d_in[4];
  const float* nu    = (const float*)d_in[5];
  const float* tdiag = (const float*)d_in[6];
  const float* tlow  = (const float*)d_in[7];
  float* ws = (float*)d_ws;
  float* L    = ws + OFF_L;
  float* W    = ws + OFF_W;
  float* mu   = ws + OFF_MU;
  float* Y    = ws + OFF_Y;
  float* z    = ws + OFF_Z;
  float* wm   = ws + OFF_WM;
  float* u    = ws + OFF_U;
  float* cst  = ws + OFF_CONST;
  int*   idx  = (int*)(ws + OFF_IDX);
  int*   rmap = (int*)(ws + OFF_RMAP);
  float* zg   = ws + OFF_ZG;
  float* Vmu  = ws + OFF_VMU;
  float* muBmu= ws + OFF_MUBMU;
  float* mun  = ws + OFF_MUN;
  float* Minv = ws + OFF_MINV;
  float* bias = ws + OFF_BIAS;
  float* qB   = ws + OFF_QB;
  float* qn   = ws + OFF_QNRM;
  float* xmup = ws + OFF_XMU;
  float* Rg   = ws + OFF_RG;
  unsigned short* P  = (unsigned short*)(ws + OFF_P);
  unsigned short* PX = (unsigned short*)(ws + OFF_PX);
  unsigned short* PW = (unsigned short*)(ws + OFF_PW);
  float* Ttmp = ws + OFF_RG;       // trinv scratch, reused (Rg written later)
  float* out  = (float*)d_out;

  // F1: init (L/W/PW) + consts + classidx + mu/mun(+PX) + diag-inv(+PW) + PX(Xq/Xs)
  f_init<<<1161 + 768, 256, 0, stream>>>(tdiag, tlow, kappa, nu, labels, Xs, Xq, m,
                                         L, W, cst, idx, rmap, mu, mun, PX, PW);
  // trinv recursive doubling; level-128 T fused with xmu partials; triX emits PW
  k_triT128_xmu<<<260, 256, 0, stream>>>(L, W, Ttmp, Xq, mu, xmup);
  k_triX<<<4, 256, 0, stream>>>(W, Ttmp, 128, PW);
  k_triT<<<8, 256, 0, stream>>>(L, W, Ttmp, 256);
  k_triX<<<8, 256, 0, stream>>>(W, Ttmp, 256, PW);
  k_triT<<<16, 256, 0, stream>>>(L, W, Ttmp, 512);
  k_triX<<<16, 256, 0, stream>>>(W, Ttmp, 512, PW);
  // Y via 4-combo split MFMA (tri-skip) + wm; emits Y fp32 + P
  f_y_wm<<<520, 256, 0, stream>>>(PX, PW, W, m, Y, P, wm);
  // u = W^T wm + SM consts
  k_uB<<<513, 256, 0, stream>>>(W, L, wm, u, cst);
  // Rg: fused 2-pass split MFMA (single buffer) + query z/qn/qB
  f_z_rg<<<544 + 512, 256, 0, stream>>>(P, Y, rmap, Xq, u, cst, Rg, z, qn, qB);
  // Gram (zs = Y.wm) + 17x17 inverse + bias
  k_gramminv<<<64, 256, 0, stream>>>(Y, wm, rmap, cst, zg, Vmu, muBmu, Minv, bias);
  k_logits<<<dim3(QNQ / 256, CNUM), 256, 0, stream>>>(Rg, z, zg, Vmu, muBmu,
                                                      mun, qB, qn, xmup, Minv, bias,
                                                      cst, out);
  (void)in_sizes; (void)n_in; (void)out_size; (void)ws_size;
}